// Round 2
// baseline (1387.770 us; speedup 1.0000x reference)
//
#include <hip/hip_runtime.h>

typedef unsigned short u16;
typedef short v8s __attribute__((ext_vector_type(8)));
typedef u16 v8u __attribute__((ext_vector_type(8)));
typedef float v4f __attribute__((ext_vector_type(4)));
typedef __bf16 v8bf __attribute__((ext_vector_type(8)));

__device__ __forceinline__ float bf2f(u16 u) {
    unsigned x = ((unsigned)u) << 16; float f; __builtin_memcpy(&f, &x, 4); return f;
}
__device__ __forceinline__ u16 f2bf(float f) {
    unsigned x; __builtin_memcpy(&x, &f, 4);
    x = x + 0x7FFFu + ((x >> 16) & 1u);
    return (u16)(x >> 16);
}
__device__ __forceinline__ float silu(float v) { return v / (1.f + __expf(-v)); }

// async global->LDS 16B per lane; l must be wave-uniform, data lands at l+lane*16
__device__ __forceinline__ void gld16(const void* g, void* l) {
    __builtin_amdgcn_global_load_lds(
        (const __attribute__((address_space(1))) unsigned int*)(uintptr_t)g,
        (__attribute__((address_space(3))) unsigned int*)(unsigned int)(uintptr_t)l,
        16, 0, 0);
}

// ---------------------------------------------------------------------------
// Weight conversion / reshuffle kernels (fp32 in -> bf16 out)
// ---------------------------------------------------------------------------
__global__ void cvtw(const float* __restrict__ in, u16* __restrict__ out, int n) {
    int i = blockIdx.x * 256 + threadIdx.x;
    if (i < n) out[i] = f2bf(in[i]);
}
// 3x3: in[co][ci][tap(9)] -> out[tap][co][ci]   (128x128x9)
__global__ void wtrans3(const float* __restrict__ in, u16* __restrict__ out) {
    int i = blockIdx.x * 256 + threadIdx.x;
    if (i >= 147456) return;
    int tap = i % 9; int rem = i / 9; int ci = rem & 127; int co = rem >> 7;
    out[((tap * 128 + co) << 7) + ci] = f2bf(in[i]);
}
// pixel-unshuffle 1x1: in[co][c*R2+tap] -> out[tap][co][c]  (co=128, c=128)
__global__ void wtrans_ps(const float* __restrict__ in, u16* __restrict__ out, int R2) {
    int i = blockIdx.x * 256 + threadIdx.x;
    int tap = i % R2; int rem = i / R2; int c = rem & 127; int co = rem >> 7;
    out[((tap * 128 + co) << 7) + c] = f2bf(in[i]);
}

// ---------------------------------------------------------------------------
// NCHW fp32 -> NHWC bf16 transpose for x (C=256, HW=16384)
// ---------------------------------------------------------------------------
__global__ __launch_bounds__(256) void nchw2nhwc(const float* __restrict__ in, u16* __restrict__ out) {
    __shared__ u16 tile[64][72];
    const int n = blockIdx.z, c0 = blockIdx.y * 64, p0 = blockIdx.x * 64;
#pragma unroll
    for (int rep = 0; rep < 16; ++rep) {
        int idx = rep * 256 + threadIdx.x;
        int c = idx >> 6, p = idx & 63;
        tile[c][p] = f2bf(in[((size_t)(n * 256 + c0 + c)) * 16384 + p0 + p]);
    }
    __syncthreads();
#pragma unroll
    for (int rep = 0; rep < 16; ++rep) {
        int idx = rep * 256 + threadIdx.x;
        int p = idx >> 6, c = idx & 63;
        out[((size_t)n * 16384 + p0 + p) * 256 + c0 + c] = tile[c][p];
    }
}

// ---------------------------------------------------------------------------
// conv3_mfma v3: 3x3 s1 p1, Cin=128 (slice c0 of srcC), Cout=128, H=W=128.
// Block = 1 output row (128 px) x 128 co, 4 waves 2x2.
// - A staged CONTIGUOUSLY: [3 rows][128px][64ci-half] = 48KB, single buffer,
//   two ci-halves per block. Per-px 128B runs -> full-line HBM efficiency.
// - XOR swizzle (bits4-6 ^= px&7) on LDS; store-side pre-swizzled source.
// - B (weights) never inside the MFMA loop from cold: 12-load per-kh register
//   pipeline, issued while previous kh computes; no staging outstanding
//   during compute so B waits are short counted vmcnt.
// - XCD-chunked h swizzle: 16 consecutive rows per XCD -> neighbor-row L2 hit.
// - Epilogue transposed through LDS -> 16B coalesced stores (kills the 2x
//   write amplification of 2B scatter stores).
// ---------------------------------------------------------------------------
__global__ __launch_bounds__(256, 2) void conv3_mfma(
    const u16* __restrict__ src, int c0, int srcC,
    const u16* __restrict__ wt,  // [9][128][128]
    const float* __restrict__ scale, const float* __restrict__ bias,
    u16* __restrict__ out) {
    __shared__ __align__(16) char smem[49152];  // 48KB stage / 34.8KB epilogue
    const int n = blockIdx.y;
    const int hraw = blockIdx.x;
    const int h = ((hraw & 7) << 4) | (hraw >> 3);  // XCD-chunked, bijective
    const int tid = threadIdx.x;
    const int lane = tid & 63;
    const int wv = tid >> 6;
    const int r = lane & 15, q = lane >> 4;
    const int wr = wv >> 1, wc = wv & 1;

    v4f acc[4][4];
#pragma unroll
    for (int a = 0; a < 4; ++a)
#pragma unroll
        for (int b = 0; b < 4; ++b) acc[a][b] = (v4f){0.f, 0.f, 0.f, 0.f};

    const size_t rowstride = (size_t)128 * srcC;  // u16 units
    const u16* nbase = src + (size_t)n * 128 * rowstride + c0;

    // Stage one ci-half: 48 x 1KB instrs; wave wv owns t = wv*12 .. wv*12+11.
    // LDS linear offset of (t, lane) = t*1024 + lane*16.
    auto stage = [&](int koff) {
#pragma unroll
        for (int j = 0; j < 12; ++j) {
            int t = wv * 12 + j;
            int kh = t >> 4;            // wave-uniform
            int hh = h + kh - 1;
            char* dst = smem + t * 1024;  // wave-uniform base
            if ((unsigned)hh < 128u) {
                int px = ((t & 15) << 3) + (lane >> 3);
                int cb = (lane & 7) * 16;
                cb ^= (px & 7) << 4;    // inverse swizzle on SOURCE
                const char* g = (const char*)(nbase + (size_t)hh * rowstride + koff)
                                + (size_t)px * srcC * 2 + cb;
                gld16(g, dst);
            } else {
                *(v8s*)(dst + lane * 16) = (v8s){0, 0, 0, 0, 0, 0, 0, 0};
            }
        }
    };

    // load B fragments for one kh row (3 kw taps x 4 nt)
    auto loadB = [&](v8bf (&B)[12], int kh, int koff, int k0l) {
#pragma unroll
        for (int kw = 0; kw < 3; ++kw)
#pragma unroll
            for (int nt = 0; nt < 4; ++nt)
                B[kw * 4 + nt] = __builtin_bit_cast(v8bf, *(const v8s*)(
                    wt + (size_t)((kh * 3 + kw) * 128 + wc * 64 + nt * 16 + r) * 128
                       + koff + k0l + q * 8));
    };

    // compute one kh row (48 MFMA) from LDS A + register B
    auto comp = [&](v8bf (&B)[12], int kh, int k0l) {
#pragma unroll
        for (int kw = 0; kw < 3; ++kw) {
            v8bf afr[4];
#pragma unroll
            for (int mt = 0; mt < 4; ++mt) {
                int p = wr * 64 + mt * 16 + r + kw - 1;
                bool vp = (unsigned)p < 128u;
                int pc = vp ? p : 0;
                int o = kh * 16384 + pc * 128 + k0l * 2 + q * 16;
                o ^= (pc & 7) << 4;     // same involution as store side
                v8s av = *(const v8s*)(smem + o);
                if (!vp) av = (v8s){0, 0, 0, 0, 0, 0, 0, 0};
                afr[mt] = __builtin_bit_cast(v8bf, av);
            }
#pragma unroll
            for (int mt = 0; mt < 4; ++mt)
#pragma unroll
                for (int nt = 0; nt < 4; ++nt)
                    acc[mt][nt] = __builtin_amdgcn_mfma_f32_16x16x32_bf16(
                        afr[mt], B[kw * 4 + nt], acc[mt][nt], 0, 0, 0);
        }
    };

#pragma unroll
    for (int hf = 0; hf < 2; ++hf) {
        const int koff = hf * 64;
        __syncthreads();     // safe to overwrite stage buffer
        stage(koff);
        __syncthreads();     // drain -> LDS valid
#pragma unroll
        for (int k0l = 0; k0l < 64; k0l += 32) {
            v8bf bA[12], bB[12];
            loadB(bA, 0, koff, k0l);   // counted waits: bA ready at vmcnt(12)
            loadB(bB, 1, koff, k0l);
            comp(bA, 0, k0l);
            loadB(bA, 2, koff, k0l);   // reuse regs, hides under kh=1 compute
            comp(bB, 1, k0l);
            comp(bA, 2, k0l);
        }
    }

    // epilogue: transpose through LDS, then 16B coalesced stores
    __syncthreads();
    u16* ldsO = (u16*)smem;  // [128 px][136 co-padded]
#pragma unroll
    for (int nt = 0; nt < 4; ++nt) {
        int co = wc * 64 + nt * 16 + r;
        float s = scale[co], bi = bias[co];
#pragma unroll
        for (int mt = 0; mt < 4; ++mt) {
#pragma unroll
            for (int i = 0; i < 4; ++i) {
                int p = wr * 64 + mt * 16 + q * 4 + i;
                ldsO[p * 136 + co] = f2bf(silu(acc[mt][nt][i] * s + bi));
            }
        }
    }
    __syncthreads();
    const size_t obase = ((size_t)n * 128 + h) * 128;
#pragma unroll
    for (int rep = 0; rep < 8; ++rep) {
        int px = rep * 16 + (tid >> 4);
        int c8 = (tid & 15) * 8;
        *(v8u*)(out + (obase + px) * 128 + c8) = *(const v8u*)&ldsO[px * 136 + c8];
    }
}

// ---------------------------------------------------------------------------
// conv1_mfma v3: 1x1 conv, K=srcC, output NHWC bf16. Block 128px x 128co.
// - B register double-buffer, loads issued BEFORE staging (counted vmcnt,
//   staging stays in flight).
// - Epilogue transposed through LDS -> 16B coalesced stores.
// ---------------------------------------------------------------------------
__global__ __launch_bounds__(256) void conv1_mfma(
    const u16* __restrict__ src, int srcC,
    const u16* __restrict__ wt,  // [Cout][srcC]
    const float* __restrict__ scale, const float* __restrict__ bias,
    u16* __restrict__ out, int Cout) {
    __shared__ __align__(16) char smem[34816];  // 2x16KB stage / 34.8KB epilogue
    const int n = blockIdx.z, co0 = blockIdx.y * 128, px0 = blockIdx.x * 128;
    const int tid = threadIdx.x;
    const int lane = tid & 63, wv = tid >> 6;
    const int r = lane & 15, q = lane >> 4;
    const int wr = wv >> 1, wc = wv & 1;

    v4f acc[4][4];
#pragma unroll
    for (int a = 0; a < 4; ++a)
#pragma unroll
        for (int b = 0; b < 4; ++b) acc[a][b] = (v4f){0.f, 0.f, 0.f, 0.f};

    const u16* abase = src + ((size_t)n * 16384 + px0) * srcC;

    auto stage = [&](int buf, int k0) {
#pragma unroll
        for (int j = 0; j < 4; ++j) {
            int o = j * 4096 + tid * 16;
            int s2 = o ^ ((o >> 3) & 0x70);
            int px = s2 >> 7, cb = s2 & 127;
            gld16((const char*)(abase + (size_t)px * srcC + k0) + cb,
                  smem + buf * 16384 + j * 4096 + wv * 1024);
        }
    };
    auto loadB = [&](v8bf (&B)[2][4], int k0) {
        const u16* wrow = wt + (size_t)(co0 + wc * 64 + r) * srcC + k0 + q * 8;
#pragma unroll
        for (int s = 0; s < 2; ++s)
#pragma unroll
            for (int nt = 0; nt < 4; ++nt)
                B[s][nt] = __builtin_bit_cast(v8bf,
                    *(const v8s*)(wrow + s * 32 + (size_t)nt * 16 * srcC));
    };

    v8bf bcur[2][4], bnxt[2][4];
    loadB(bcur, 0);   // issued before any staging -> short counted wait
    stage(0, 0);
    int buf = 0;
    for (int k0 = 0; k0 < srcC; k0 += 64, buf ^= 1) {
        __syncthreads();
        bool more = (k0 + 64 < srcC);
        if (more) {
            loadB(bnxt, k0 + 64);      // B first...
            stage(buf ^ 1, k0 + 64);   // ...then staging: B wait never drains it
        }
#pragma unroll
        for (int s = 0; s < 2; ++s) {
            v8bf afr[4];
#pragma unroll
            for (int mt = 0; mt < 4; ++mt) {
                int ba = buf * 16384 + (wr * 64 + mt * 16 + r) * 128 + s * 64 + q * 16;
                ba ^= (ba >> 3) & 0x70;
                afr[mt] = __builtin_bit_cast(v8bf, *(const v8s*)(smem + ba));
            }
#pragma unroll
            for (int mt = 0; mt < 4; ++mt)
#pragma unroll
                for (int nt = 0; nt < 4; ++nt)
                    acc[mt][nt] = __builtin_amdgcn_mfma_f32_16x16x32_bf16(
                        afr[mt], bcur[s][nt], acc[mt][nt], 0, 0, 0);
        }
        if (more) {
#pragma unroll
            for (int s = 0; s < 2; ++s)
#pragma unroll
                for (int nt = 0; nt < 4; ++nt) bcur[s][nt] = bnxt[s][nt];
        }
    }

    // epilogue: transpose through LDS, 16B coalesced stores
    __syncthreads();
    u16* ldsO = (u16*)smem;  // [128 px][136]
#pragma unroll
    for (int nt = 0; nt < 4; ++nt) {
        int co = co0 + wc * 64 + nt * 16 + r;
        float s = scale[co], bi = bias[co];
#pragma unroll
        for (int mt = 0; mt < 4; ++mt) {
#pragma unroll
            for (int i = 0; i < 4; ++i) {
                int p = wr * 64 + mt * 16 + q * 4 + i;
                ldsO[p * 136 + (wc * 64 + nt * 16 + r)] = f2bf(silu(acc[mt][nt][i] * s + bi));
            }
        }
    }
    __syncthreads();
#pragma unroll
    for (int rep = 0; rep < 8; ++rep) {
        int px = rep * 16 + (tid >> 4);
        int c8 = (tid & 15) * 8;
        *(v8u*)(out + ((size_t)n * 16384 + px0 + px) * Cout + co0 + c8) =
            *(const v8u*)&ldsO[px * 136 + c8];
    }
}

// ---------------------------------------------------------------------------
// cat_mfma v3: cv2 = 1x1 over implicit concat [t(256), y1, y2, y3] -> 256.
// Flat 10-chunk loop; B register double-buffer issued before staging.
// Output NCHW fp32 (float4 stores, already 16B).
// ---------------------------------------------------------------------------
__global__ __launch_bounds__(256) void cat_mfma(
    const u16* __restrict__ s0, const u16* __restrict__ s1,
    const u16* __restrict__ s2, const u16* __restrict__ s3,
    const u16* __restrict__ wt,  // [256][640]
    const float* __restrict__ scale, const float* __restrict__ bias,
    float* __restrict__ out) {
    __shared__ __align__(16) u16 lds[2][128][64];
    const int n = blockIdx.z, co0 = blockIdx.y * 128, px0 = blockIdx.x * 128;
    const int tid = threadIdx.x;
    const int lane = tid & 63, wv = tid >> 6;
    const int r = lane & 15, q = lane >> 4;
    const int wr = wv >> 1, wc = wv & 1;

    v4f acc[4][4];
#pragma unroll
    for (int a = 0; a < 4; ++a)
#pragma unroll
        for (int b = 0; b < 4; ++b) acc[a][b] = (v4f){0.f, 0.f, 0.f, 0.f};

    const u16* srcs[4] = {s0, s1, s2, s3};
    const int sCq[4] = {256, 128, 128, 128};
    const int kbq[4] = {0, 256, 384, 512};
    const int segs[10] = {0, 0, 0, 0, 1, 1, 2, 2, 3, 3};
    const int k0s[10] = {0, 64, 128, 192, 0, 64, 0, 64, 0, 64};

    auto stage = [&](int buf, int c) {
        int seg = segs[c]; int sc = sCq[seg]; int k0 = k0s[c];
        const u16* ab = srcs[seg] + ((size_t)n * 16384 + px0) * sc;
#pragma unroll
        for (int j = 0; j < 4; ++j) {
            int o = j * 4096 + tid * 16;
            int s2 = o ^ ((o >> 3) & 0x70);
            int px = s2 >> 7, cb = s2 & 127;
            gld16((const char*)(ab + (size_t)px * sc + k0) + cb,
                  (char*)&lds[buf][0][0] + j * 4096 + wv * 1024);
        }
    };
    auto loadB = [&](v8bf (&B)[2][4], int c) {
        const u16* wrow = wt + (size_t)(co0 + wc * 64 + r) * 640 + kbq[segs[c]] + k0s[c] + q * 8;
#pragma unroll
        for (int s = 0; s < 2; ++s)
#pragma unroll
            for (int nt = 0; nt < 4; ++nt)
                B[s][nt] = __builtin_bit_cast(v8bf,
                    *(const v8s*)(wrow + s * 32 + (size_t)nt * 16 * 640));
    };

    v8bf bcur[2][4], bnxt[2][4];
    loadB(bcur, 0);
    stage(0, 0);
    int buf = 0;
#pragma unroll
    for (int c = 0; c < 10; ++c, buf ^= 1) {
        __syncthreads();
        if (c < 9) {
            loadB(bnxt, c + 1);
            stage(buf ^ 1, c + 1);
        }
#pragma unroll
        for (int s = 0; s < 2; ++s) {
            v8bf afr[4];
#pragma unroll
            for (int mt = 0; mt < 4; ++mt) {
                int ba = (wr * 64 + mt * 16 + r) * 128 + s * 64 + q * 16;
                ba ^= (ba >> 3) & 0x70;
                afr[mt] = __builtin_bit_cast(v8bf,
                    *(const v8s*)((const char*)&lds[buf][0][0] + ba));
            }
#pragma unroll
            for (int mt = 0; mt < 4; ++mt)
#pragma unroll
                for (int nt = 0; nt < 4; ++nt)
                    acc[mt][nt] = __builtin_amdgcn_mfma_f32_16x16x32_bf16(
                        afr[mt], bcur[s][nt], acc[mt][nt], 0, 0, 0);
        }
        if (c < 9) {
#pragma unroll
            for (int s = 0; s < 2; ++s)
#pragma unroll
                for (int nt = 0; nt < 4; ++nt) bcur[s][nt] = bnxt[s][nt];
        }
    }

#pragma unroll
    for (int nt = 0; nt < 4; ++nt) {
        int co = co0 + wc * 64 + nt * 16 + r;
        float s = scale[co], bi = bias[co];
#pragma unroll
        for (int mt = 0; mt < 4; ++mt) {
            int p = px0 + wr * 64 + mt * 16 + q * 4;
            v4f o;
#pragma unroll
            for (int i = 0; i < 4; ++i) o[i] = silu(acc[mt][nt][i] * s + bi);
            *(v4f*)(out + (size_t)(n * 256 + co) * 16384 + p) = o;
        }
    }
}

// ---------------------------------------------------------------------------
// Generic MFMA conv (kept for cvm2/cvm3 strided taps; minor cost)
// ---------------------------------------------------------------------------
template <int KH, int KW, int S, int PAD, int CIN>
__global__ __launch_bounds__(256) void conv_mfma(
    const u16* __restrict__ src, int c0, int srcC,
    const u16* __restrict__ wt,
    const float* __restrict__ scale, const float* __restrict__ bias,
    u16* __restrict__ out, int Hin, int Win, int Wout, int Cout) {
    const int n = blockIdx.z;
    const int co0 = blockIdx.y * 64;
    const int hw0 = blockIdx.x * 64;
    const int tid = threadIdx.x;
    const int lane = tid & 63, wv = tid >> 6;
    const int r = lane & 15, q = lane >> 4;
    const int wr = wv >> 1, wc = wv & 1;

    const int m0 = hw0 + wr * 32 + r;
    const int m1 = m0 + 16;
    const int h0 = m0 / Wout, w0 = m0 - h0 * Wout;
    const int h1 = m1 / Wout, w1 = m1 - h1 * Wout;

    v4f acc00 = {0.f, 0.f, 0.f, 0.f}, acc01 = {0.f, 0.f, 0.f, 0.f};
    v4f acc10 = {0.f, 0.f, 0.f, 0.f}, acc11 = {0.f, 0.f, 0.f, 0.f};

    const u16* b0base = wt + (size_t)(co0 + wc * 32 + r) * CIN + q * 8;
    const size_t wtap = (size_t)Cout * CIN;

    int tap = 0;
#pragma unroll
    for (int kh = 0; kh < KH; ++kh)
#pragma unroll
        for (int kw = 0; kw < KW; ++kw, ++tap) {
            int ih0 = h0 * S + kh - PAD, iw0 = w0 * S + kw - PAD;
            int ih1 = h1 * S + kh - PAD, iw1 = w1 * S + kw - PAD;
            bool v0 = ((unsigned)ih0 < (unsigned)Hin) & ((unsigned)iw0 < (unsigned)Win);
            bool v1 = ((unsigned)ih1 < (unsigned)Hin) & ((unsigned)iw1 < (unsigned)Win);
            int p0i = v0 ? (n * Hin + ih0) * Win + iw0 : 0;
            int p1i = v1 ? (n * Hin + ih1) * Win + iw1 : 0;
            const u16* a0 = src + (size_t)p0i * srcC + c0 + q * 8;
            const u16* a1 = src + (size_t)p1i * srcC + c0 + q * 8;
            const u16* b0 = b0base + (size_t)tap * wtap;
            const u16* b1 = b0 + (size_t)16 * CIN;
#pragma unroll
            for (int k = 0; k < CIN; k += 32) {
                v8s za = {0, 0, 0, 0, 0, 0, 0, 0};
                v8s a0s = za, a1s = za;
                if (v0) a0s = *(const v8s*)(a0 + k);
                if (v1) a1s = *(const v8s*)(a1 + k);
                v8s b0s = *(const v8s*)(b0 + k);
                v8s b1s = *(const v8s*)(b1 + k);
                v8bf af0 = __builtin_bit_cast(v8bf, a0s);
                v8bf af1 = __builtin_bit_cast(v8bf, a1s);
                v8bf bw0 = __builtin_bit_cast(v8bf, b0s);
                v8bf bw1 = __builtin_bit_cast(v8bf, b1s);
                acc00 = __builtin_amdgcn_mfma_f32_16x16x32_bf16(af0, bw0, acc00, 0, 0, 0);
                acc01 = __builtin_amdgcn_mfma_f32_16x16x32_bf16(af0, bw1, acc01, 0, 0, 0);
                acc10 = __builtin_amdgcn_mfma_f32_16x16x32_bf16(af1, bw0, acc10, 0, 0, 0);
                acc11 = __builtin_amdgcn_mfma_f32_16x16x32_bf16(af1, bw1, acc11, 0, 0, 0);
            }
        }

    const int HWo = gridDim.x * 64;
#pragma unroll
    for (int ct = 0; ct < 2; ++ct) {
        v4f av0 = ct ? acc01 : acc00;
        v4f av1 = ct ? acc11 : acc10;
        int co = co0 + wc * 32 + ct * 16 + r;
        float s = scale[co], bb = bias[co];
        int mb = hw0 + wr * 32 + q * 4;
#pragma unroll
        for (int i = 0; i < 4; ++i) {
            float x0 = av0[i] * s + bb;
            float x1 = av1[i] * s + bb;
            out[((size_t)n * HWo + mb + i) * Cout + co] = f2bf(silu(x0));
            out[((size_t)n * HWo + mb + 16 + i) * Cout + co] = f2bf(silu(x1));
        }
    }
}

// ---------------------------------------------------------------------------
// u2 carafe == nearest 2x upsample (+ residual y1). NHWC bf16, C=128.
// ---------------------------------------------------------------------------
__global__ __launch_bounds__(256) void k_upadd(const u16* __restrict__ y2a,
                                               const u16* __restrict__ y1,
                                               u16* __restrict__ out) {
    int t = blockIdx.x * 256 + threadIdx.x;  // 2,097,152
    int cg = t & 15; int pix = t >> 4;
    int n = pix >> 14; int p = pix & 16383; int ho = p >> 7; int wo = p & 127;
    const u16* a = y2a + ((size_t)((n * 64 + (ho >> 1)) * 64 + (wo >> 1))) * 128 + cg * 8;
    const u16* b = y1 + (size_t)pix * 128 + cg * 8;
    v8s av = *(const v8s*)a;
    v8s bv = *(const v8s*)b;
    v8u o;
#pragma unroll
    for (int e = 0; e < 8; ++e) o[e] = f2bf(bf2f((u16)av[e]) + bf2f((u16)bv[e]));
    *(v8u*)(out + (size_t)pix * 128 + cg * 8) = o;
}

// ---------------------------------------------------------------------------
// u3 carafe pieces (small spatial, scalar fp32 math)
// ---------------------------------------------------------------------------
__global__ __launch_bounds__(256) void k_u3down(const u16* __restrict__ y3a,
                                                const float* __restrict__ w,
                                                const float* __restrict__ b,
                                                float* __restrict__ ktA) {
    int t = blockIdx.x * 256 + threadIdx.x;  // 262,144
    int co = t & 31; int pix = t >> 5;
    const u16* xr = y3a + (size_t)pix * 128;
    const float* wr = w + (size_t)co * 128;
    float acc = b[co];
#pragma unroll 16
    for (int k = 0; k < 128; ++k) acc += bf2f(xr[k]) * wr[k];
    ktA[t] = acc;
}

__global__ __launch_bounds__(256) void k_u3enc(const float* __restrict__ ktA,
                                               const float* __restrict__ ew,
                                               const float* __restrict__ eb,
                                               float* __restrict__ wtsm) {
    int t = blockIdx.x * 256 + threadIdx.x;  // 131,072
    int r = t & 15; int pix = t >> 4;
    int n = pix >> 10; int hw = pix & 1023; int h = hw >> 5; int w = hw & 31;
    float v[4];
#pragma unroll
    for (int kk = 0; kk < 4; ++kk) {
        int co = kk * 16 + r;
        float acc = eb[co];
#pragma unroll
        for (int dh = 0; dh < 2; ++dh)
#pragma unroll
            for (int dw = 0; dw < 2; ++dw) {
                int hh = h - 1 + dh, ww = w - 1 + dw;
                if (hh < 0 || ww < 0) continue;
                const float* kp = ktA + ((size_t)((n * 32 + hh) * 32 + ww)) * 32;
                const float* wp = ew + (size_t)co * 128 + dh * 2 + dw;
                for (int ci = 0; ci < 32; ++ci) acc += kp[ci] * wp[ci * 4];
            }
        v[kk] = acc;
    }
    float mx = fmaxf(fmaxf(v[0], v[1]), fmaxf(v[2], v[3]));
    float e0 = __expf(v[0] - mx), e1 = __expf(v[1] - mx), e2 = __expf(v[2] - mx), e3 = __expf(v[3] - mx);
    float inv = 1.f / (e0 + e1 + e2 + e3);
    float* o = wtsm + (size_t)t * 4;
    o[0] = e0 * inv; o[1] = e1 * inv; o[2] = e2 * inv; o[3] = e3 * inv;
}

__global__ __launch_bounds__(256) void k_carafe(const u16* __restrict__ y3a,
                                                const float* __restrict__ wtsm,
                                                const u16* __restrict__ y2,
                                                u16* __restrict__ out) {
    int t = blockIdx.x * 256 + threadIdx.x;  // 2,097,152
    int cg = t & 15; int pix = t >> 4;
    int n = pix >> 14; int p = pix & 16383; int ho = p >> 7; int wo = p & 127;
    int h = ho >> 2, i = ho & 3, w = wo >> 2, j = wo & 3, r = i * 4 + j;
    const float* wv = wtsm + ((size_t)((n * 1024 + h * 32 + w) * 16 + r)) * 4;
    v8s yv = *(const v8s*)(y2 + (size_t)pix * 128 + cg * 8);
    float acc[8];
#pragma unroll
    for (int e = 0; e < 8; ++e) acc[e] = bf2f((u16)yv[e]);
#pragma unroll
    for (int kk = 0; kk < 4; ++kk) {
        int ki = kk >> 1, kj = kk & 1;
        int hh = h + ki - 1, ww = w + kj - 1;
        if (hh < 0 || ww < 0) continue;
        float wk = wv[kk];
        v8s sv = *(const v8s*)(y3a + ((size_t)((n * 32 + hh) * 32 + ww)) * 128 + cg * 8);
#pragma unroll
        for (int e = 0; e < 8; ++e) acc[e] += wk * bf2f((u16)sv[e]);
    }
    v8u o;
#pragma unroll
    for (int e = 0; e < 8; ++e) o[e] = f2bf(acc[e]);
    *(v8u*)(out + (size_t)pix * 128 + cg * 8) = o;
}

// ---------------------------------------------------------------------------
extern "C" void kernel_launch(void* const* d_in, const int* in_sizes, int n_in,
                              void* d_out, int out_size, void* d_ws, size_t ws_size,
                              hipStream_t stream) {
    const float* x     = (const float*)d_in[0];
    const float* cv1_w = (const float*)d_in[1];
    const float* cv1_s = (const float*)d_in[2];
    const float* cv1_b = (const float*)d_in[3];
    const float* m1a_w = (const float*)d_in[4];
    const float* m1a_s = (const float*)d_in[5];
    const float* m1a_b = (const float*)d_in[6];
    const float* m1b_w = (const float*)d_in[7];
    const float* m1b_s = (const float*)d_in[8];
    const float* m1b_b = (const float*)d_in[9];
    const float* m2a_w = (const float*)d_in[10];
    const float* m2a_s = (const float*)d_in[11];
    const float* m2a_b = (const float*)d_in[12];
    const float* m2b_w = (const float*)d_in[13];
    const float* m2b_s = (const float*)d_in[14];
    const float* m2b_b = (const float*)d_in[15];
    const float* m3a_w = (const float*)d_in[16];
    const float* m3a_s = (const float*)d_in[17];
    const float* m3a_b = (const float*)d_in[18];
    const float* m3b_w = (const float*)d_in[19];
    const float* m3b_s = (const float*)d_in[20];
    const float* m3b_b = (const float*)d_in[21];
    const float* cvm2_w = (const float*)d_in[22];
    const float* cvm2_s = (const float*)d_in[23];
    const float* cvm2_b = (const float*)d_in[24];
    const float* cvm3_w = (const float*)d_in[25];
    const float* cvm3_s = (const float*)d_in[26];
    const float* cvm3_b = (const float*)d_in[27];
    // d_in[28..31]: u2_down_w/b, u2_enc_w/b — dead (k=1 softmax == 1)
    const float* u3_down_w = (const float*)d_in[32];
    const float* u3_down_b = (const float*)d_in[33];
    const float* u3_enc_w  = (const float*)d_in[34];
    const float* u3_enc_b  = (const float*)d_in[35];
    const float* cv2_w = (const float*)d_in[36];
    const float* cv2_s = (const float*)d_in[37];
    const float* cv2_b = (const float*)d_in[38];

    char* ws = (char*)d_ws;
    u16* A    = (u16*)(ws + 0);          // x_nhwc (67MB); later y2/y3
    u16* t    = (u16*)(ws + 67108864);   // 67MB
    u16* y1   = (u16*)(ws + 134217728);  // 33.5MB
    u16* bt   = (u16*)(ws + 167772160);  // 33.5MB bneck tmp
    u16* te   = (u16*)(ws + 201326592);  // 33.5MB y2b / y3b
    u16* y2a  = (u16*)(ws + 234881024);  // 8.4MB
    u16* y3a  = (u16*)(ws + 243269632);  // 2.1MB
    float* ktA = (float*)(ws + 245366784);  // 1MB fp32
    float* wts = (float*)(ws + 246415360);  // 2MB fp32
    u16* w3t  = (u16*)(ws + 248512512);  // 6 x 147456 bf16
    u16* wu2  = (u16*)(ws + 250281984);  // 65536 bf16
    u16* wu4  = (u16*)(ws + 250413056);  // 262144 bf16
    u16* wc1  = (u16*)(ws + 250937344);  // 65536 bf16
    u16* wc2  = (u16*)(ws + 251068416);  // 163840 bf16
    u16* y2 = A;
    u16* y3 = A + 16777216;

    dim3 B(256);
    // weight conversions / reshuffles
    wtrans3<<<576, B, 0, stream>>>(m1a_w, w3t + 0 * 147456);
    wtrans3<<<576, B, 0, stream>>>(m1b_w, w3t + 1 * 147456);
    wtrans3<<<576, B, 0, stream>>>(m2a_w, w3t + 2 * 147456);
    wtrans3<<<576, B, 0, stream>>>(m2b_w, w3t + 3 * 147456);
    wtrans3<<<576, B, 0, stream>>>(m3a_w, w3t + 4 * 147456);
    wtrans3<<<576, B, 0, stream>>>(m3b_w, w3t + 5 * 147456);
    wtrans_ps<<<256, B, 0, stream>>>(cvm2_w, wu2, 4);
    wtrans_ps<<<1024, B, 0, stream>>>(cvm3_w, wu4, 16);
    cvtw<<<256, B, 0, stream>>>(cv1_w, wc1, 65536);
    cvtw<<<640, B, 0, stream>>>(cv2_w, wc2, 163840);

    // x -> NHWC bf16
    nchw2nhwc<<<dim3(256, 4, 8), B, 0, stream>>>(x, A);

    // cv1 (1x1 256->256) -> t  (y = ch 0..127, y0 = ch 128..255)
    conv1_mfma<<<dim3(128, 2, 8), B, 0, stream>>>(A, 256, wc1, cv1_s, cv1_b, t, 256);

    // bneck1: y0 -> bt -> y1
    conv3_mfma<<<dim3(128, 8), B, 0, stream>>>(t, 128, 256, w3t + 0 * 147456, m1a_s, m1a_b, bt);
    conv3_mfma<<<dim3(128, 8), B, 0, stream>>>(bt, 0, 128, w3t + 1 * 147456, m1b_s, m1b_b, y1);

    // cvm2: pixel_unshuffle(y1,2) + 1x1 == 2x2/stride2 conv -> y2a (64x64)
    conv_mfma<2, 2, 2, 0, 128><<<dim3(64, 2, 8), B, 0, stream>>>(
        y1, 0, 128, wu2, cvm2_s, cvm2_b, y2a, 128, 128, 64, 128);

    // u2 carafe == nearest 2x upsample, + y1 -> te
    k_upadd<<<8192, B, 0, stream>>>(y2a, y1, te);

    // bneck2: te -> bt -> y2
    conv3_mfma<<<dim3(128, 8), B, 0, stream>>>(te, 0, 128, w3t + 2 * 147456, m2a_s, m2a_b, bt);
    conv3_mfma<<<dim3(128, 8), B, 0, stream>>>(bt, 0, 128, w3t + 3 * 147456, m2b_s, m2b_b, y2);

    // cvm3: pixel_unshuffle(y2,4) + 1x1 == 4x4/stride4 conv -> y3a (32x32)
    conv_mfma<4, 4, 4, 0, 128><<<dim3(16, 2, 8), B, 0, stream>>>(
        y2, 0, 128, wu4, cvm3_s, cvm3_b, y3a, 128, 128, 32, 128);

    // u3 carafe (k=2, up=4)
    k_u3down<<<1024, B, 0, stream>>>(y3a, u3_down_w, u3_down_b, ktA);
    k_u3enc<<<512, B, 0, stream>>>(ktA, u3_enc_w, u3_enc_b, wts);
    k_carafe<<<8192, B, 0, stream>>>(y3a, wts, y2, te);

    // bneck3: te -> bt -> y3
    conv3_mfma<<<dim3(128, 8), B, 0, stream>>>(te, 0, 128, w3t + 4 * 147456, m3a_s, m3a_b, bt);
    conv3_mfma<<<dim3(128, 8), B, 0, stream>>>(bt, 0, 128, w3t + 5 * 147456, m3b_s, m3b_b, y3);

    // cv2: 1x1 over concat [t, y1, y2, y3] -> d_out (NCHW fp32)
    cat_mfma<<<dim3(128, 2, 8), B, 0, stream>>>(t, y1, y2, y3, wc2, cv2_s, cv2_b, (float*)d_out);
}

// Round 3
// 1377.214 us; speedup vs baseline: 1.0077x; 1.0077x over previous
//
#include <hip/hip_runtime.h>

typedef unsigned short u16;
typedef short v8s __attribute__((ext_vector_type(8)));
typedef u16 v8u __attribute__((ext_vector_type(8)));
typedef float v4f __attribute__((ext_vector_type(4)));
typedef __bf16 v8bf __attribute__((ext_vector_type(8)));

__device__ __forceinline__ float bf2f(u16 u) {
    unsigned x = ((unsigned)u) << 16; float f; __builtin_memcpy(&f, &x, 4); return f;
}
__device__ __forceinline__ u16 f2bf(float f) {
    unsigned x; __builtin_memcpy(&x, &f, 4);
    x = x + 0x7FFFu + ((x >> 16) & 1u);
    return (u16)(x >> 16);
}
__device__ __forceinline__ float silu(float v) { return v / (1.f + __expf(-v)); }

// async global->LDS 16B per lane; l must be wave-uniform, data lands at l+lane*16
__device__ __forceinline__ void gld16(const void* g, void* l) {
    __builtin_amdgcn_global_load_lds(
        (const __attribute__((address_space(1))) unsigned int*)(uintptr_t)g,
        (__attribute__((address_space(3))) unsigned int*)(unsigned int)(uintptr_t)l,
        16, 0, 0);
}

// ---------------------------------------------------------------------------
// Weight conversion / reshuffle kernels (fp32 in -> bf16 out)
// ---------------------------------------------------------------------------
__global__ void cvtw(const float* __restrict__ in, u16* __restrict__ out, int n) {
    int i = blockIdx.x * 256 + threadIdx.x;
    if (i < n) out[i] = f2bf(in[i]);
}
// 3x3: in[co][ci][tap(9)] -> out[tap][co][ci]   (128x128x9)
__global__ void wtrans3(const float* __restrict__ in, u16* __restrict__ out) {
    int i = blockIdx.x * 256 + threadIdx.x;
    if (i >= 147456) return;
    int tap = i % 9; int rem = i / 9; int ci = rem & 127; int co = rem >> 7;
    out[((tap * 128 + co) << 7) + ci] = f2bf(in[i]);
}
// pixel-unshuffle 1x1: in[co][c*R2+tap] -> out[tap][co][c]  (co=128, c=128)
__global__ void wtrans_ps(const float* __restrict__ in, u16* __restrict__ out, int R2) {
    int i = blockIdx.x * 256 + threadIdx.x;
    int tap = i % R2; int rem = i / R2; int c = rem & 127; int co = rem >> 7;
    out[((tap * 128 + co) << 7) + c] = f2bf(in[i]);
}

// ---------------------------------------------------------------------------
// NCHW fp32 -> NHWC bf16 transpose for x (C=256, HW=16384)
// ---------------------------------------------------------------------------
__global__ __launch_bounds__(256) void nchw2nhwc(const float* __restrict__ in, u16* __restrict__ out) {
    __shared__ u16 tile[64][72];
    const int n = blockIdx.z, c0 = blockIdx.y * 64, p0 = blockIdx.x * 64;
#pragma unroll
    for (int rep = 0; rep < 16; ++rep) {
        int idx = rep * 256 + threadIdx.x;
        int c = idx >> 6, p = idx & 63;
        tile[c][p] = f2bf(in[((size_t)(n * 256 + c0 + c)) * 16384 + p0 + p]);
    }
    __syncthreads();
#pragma unroll
    for (int rep = 0; rep < 16; ++rep) {
        int idx = rep * 256 + threadIdx.x;
        int p = idx >> 6, c = idx & 63;
        out[((size_t)n * 16384 + p0 + p) * 256 + c0 + c] = tile[c][p];
    }
}

// ---------------------------------------------------------------------------
// conv3_mfma v4: 3x3 s1 p1, Cin=128 (slice c0 of srcC), Cout=128, H=W=128.
// grid (256, 8): bx -> xcd = bx&7 (XCD id), h = xcd*16 + (bx>>4) (16-row
// band per XCD), cohalf = (bx>>3)&1 (co-twin lands on SAME XCD at bx+8 ->
// A rows are L2 hits for the twin).
// Block = 128px x 64co, 4 waves 2x2 (wave = 64px x 32co, acc[4][2]=32 reg).
// A: 32ci chunks [3 rows][128px][32ci] = 24KB, DOUBLE-buffered (48KB LDS,
//    3 blocks/CU), XOR-swizzled (bits4-6 ^= bits7-9), contiguous dest.
// B: 18 frags/chunk (72 VGPR), ALL issued before stage(next) so B's
//    counted vmcnt never drains the in-flight staging (in-order queue).
// One __syncthreads per chunk = the 2-phase minimum recipe.
// Epilogue via LDS transpose -> 16B coalesced stores.
// ---------------------------------------------------------------------------
__global__ __launch_bounds__(256, 3) void conv3_mfma(
    const u16* __restrict__ src, int c0, int srcC,
    const u16* __restrict__ wt,  // [9][128][128]
    const float* __restrict__ scale, const float* __restrict__ bias,
    u16* __restrict__ out) {
    __shared__ __align__(16) char smem[49152];  // 2x24KB stage / 18KB epilogue
    const int bx = blockIdx.x, n = blockIdx.y;
    const int h = ((bx & 7) << 4) | (bx >> 4);
    const int co0 = ((bx >> 3) & 1) * 64;
    const int tid = threadIdx.x;
    const int lane = tid & 63, wv = tid >> 6;
    const int r = lane & 15, q = lane >> 4;
    const int wr = wv >> 1, wc = wv & 1;

    v4f acc[4][2];
#pragma unroll
    for (int a = 0; a < 4; ++a)
#pragma unroll
        for (int b = 0; b < 2; ++b) acc[a][b] = (v4f){0.f, 0.f, 0.f, 0.f};

    const size_t rowstride = (size_t)128 * srcC;  // u16 units
    const u16* nbase = src + (size_t)n * 128 * rowstride + c0;

    // stage one 32ci chunk: 24 x 1KB instrs, wave wv owns t = wv*6..wv*6+5.
    // LDS[L] = G[sw(L)] with sw = L ^ ((L>>3)&0x70) per 8KB kh-block.
    auto stage = [&](int buf, int k0) {
#pragma unroll
        for (int j = 0; j < 6; ++j) {
            int t = wv * 6 + j;          // wave-uniform
            int kh = t >> 3;             // wave-uniform
            int hh = h + kh - 1;
            char* dst = smem + buf * 24576 + t * 1024;  // wave-uniform base
            if ((unsigned)hh < 128u) {
                int l = ((t & 7) << 10) + lane * 16;
                int sw = l ^ ((l >> 3) & 0x70);
                int px = sw >> 6, cb = sw & 63;
                gld16((const char*)(nbase + (size_t)hh * rowstride + k0)
                          + (size_t)px * srcC * 2 + cb,
                      dst);
            } else {
                *(v8s*)(dst + lane * 16) = (v8s){0, 0, 0, 0, 0, 0, 0, 0};
            }
        }
    };

    stage(0, 0);
    int buf = 0;
#pragma unroll
    for (int ch = 0; ch < 4; ++ch, buf ^= 1) {
        const int k0 = ch * 32;
        __syncthreads();  // drains vmcnt -> lds[buf] valid; safe to refill buf^1

        // B loads FIRST: their waits are counted vmcnt that leave the
        // staging gld16s (issued after) in flight.
        v8bf bfr[9][2];
#pragma unroll
        for (int tap = 0; tap < 9; ++tap)
#pragma unroll
            for (int nt = 0; nt < 2; ++nt)
                bfr[tap][nt] = __builtin_bit_cast(v8bf, *(const v8s*)(
                    wt + (size_t)((tap * 128 + co0 + wc * 32 + nt * 16 + r) << 7)
                       + k0 + q * 8));

        if (ch < 3) stage(buf ^ 1, k0 + 32);  // overlaps this chunk's compute

        const char* abase = smem + buf * 24576;
#pragma unroll
        for (int tap = 0; tap < 9; ++tap) {
            const int kh = tap / 3, kw = tap % 3;
#pragma unroll
            for (int mt = 0; mt < 4; ++mt) {
                int p = wr * 64 + mt * 16 + r + kw - 1;
                bool vp = (unsigned)p < 128u;
                int pc = vp ? p : 0;
                int b = (pc << 6) + q * 16;
                b ^= (b >> 3) & 0x70;      // same involution as store side
                v8s av = *(const v8s*)(abase + (kh << 13) + b);
                if (!vp) av = (v8s){0, 0, 0, 0, 0, 0, 0, 0};
                v8bf af = __builtin_bit_cast(v8bf, av);
#pragma unroll
                for (int nt = 0; nt < 2; ++nt)
                    acc[mt][nt] = __builtin_amdgcn_mfma_f32_16x16x32_bf16(
                        af, bfr[tap][nt], acc[mt][nt], 0, 0, 0);
            }
        }
    }

    // epilogue: transpose through LDS (pad 72 -> conflict-light), 16B stores
    __syncthreads();
    u16* ldsO = (u16*)smem;  // [128 px][72 coL]
#pragma unroll
    for (int nt = 0; nt < 2; ++nt) {
        int coL = wc * 32 + nt * 16 + r;
        int co = co0 + coL;
        float s = scale[co], bi = bias[co];
#pragma unroll
        for (int mt = 0; mt < 4; ++mt) {
#pragma unroll
            for (int i = 0; i < 4; ++i) {
                int p = wr * 64 + mt * 16 + q * 4 + i;
                ldsO[p * 72 + coL] = f2bf(silu(acc[mt][nt][i] * s + bi));
            }
        }
    }
    __syncthreads();
    const size_t obase = ((size_t)n * 128 + h) * 128;
#pragma unroll
    for (int rep = 0; rep < 4; ++rep) {
        int px = rep * 32 + (tid >> 3);
        int c8 = (tid & 7) * 8;
        *(v8u*)(out + (obase + px) * 128 + co0 + c8) = *(const v8u*)&ldsO[px * 72 + c8];
    }
}

// ---------------------------------------------------------------------------
// conv1_mfma v3: 1x1 conv, K=srcC, output NHWC bf16. Block 128px x 128co.
// - B register double-buffer, loads issued BEFORE staging (counted vmcnt,
//   staging stays in flight).
// - Epilogue transposed through LDS -> 16B coalesced stores.
// ---------------------------------------------------------------------------
__global__ __launch_bounds__(256) void conv1_mfma(
    const u16* __restrict__ src, int srcC,
    const u16* __restrict__ wt,  // [Cout][srcC]
    const float* __restrict__ scale, const float* __restrict__ bias,
    u16* __restrict__ out, int Cout) {
    __shared__ __align__(16) char smem[34816];  // 2x16KB stage / 34.8KB epilogue
    const int n = blockIdx.z, co0 = blockIdx.y * 128, px0 = blockIdx.x * 128;
    const int tid = threadIdx.x;
    const int lane = tid & 63, wv = tid >> 6;
    const int r = lane & 15, q = lane >> 4;
    const int wr = wv >> 1, wc = wv & 1;

    v4f acc[4][4];
#pragma unroll
    for (int a = 0; a < 4; ++a)
#pragma unroll
        for (int b = 0; b < 4; ++b) acc[a][b] = (v4f){0.f, 0.f, 0.f, 0.f};

    const u16* abase = src + ((size_t)n * 16384 + px0) * srcC;

    auto stage = [&](int buf, int k0) {
#pragma unroll
        for (int j = 0; j < 4; ++j) {
            int o = j * 4096 + tid * 16;
            int s2 = o ^ ((o >> 3) & 0x70);
            int px = s2 >> 7, cb = s2 & 127;
            gld16((const char*)(abase + (size_t)px * srcC + k0) + cb,
                  smem + buf * 16384 + j * 4096 + wv * 1024);
        }
    };
    auto loadB = [&](v8bf (&B)[2][4], int k0) {
        const u16* wrow = wt + (size_t)(co0 + wc * 64 + r) * srcC + k0 + q * 8;
#pragma unroll
        for (int s = 0; s < 2; ++s)
#pragma unroll
            for (int nt = 0; nt < 4; ++nt)
                B[s][nt] = __builtin_bit_cast(v8bf,
                    *(const v8s*)(wrow + s * 32 + (size_t)nt * 16 * srcC));
    };

    v8bf bcur[2][4], bnxt[2][4];
    loadB(bcur, 0);   // issued before any staging -> short counted wait
    stage(0, 0);
    int buf = 0;
    for (int k0 = 0; k0 < srcC; k0 += 64, buf ^= 1) {
        __syncthreads();
        bool more = (k0 + 64 < srcC);
        if (more) {
            loadB(bnxt, k0 + 64);      // B first...
            stage(buf ^ 1, k0 + 64);   // ...then staging: B wait never drains it
        }
#pragma unroll
        for (int s = 0; s < 2; ++s) {
            v8bf afr[4];
#pragma unroll
            for (int mt = 0; mt < 4; ++mt) {
                int ba = buf * 16384 + (wr * 64 + mt * 16 + r) * 128 + s * 64 + q * 16;
                ba ^= (ba >> 3) & 0x70;
                afr[mt] = __builtin_bit_cast(v8bf, *(const v8s*)(smem + ba));
            }
#pragma unroll
            for (int mt = 0; mt < 4; ++mt)
#pragma unroll
                for (int nt = 0; nt < 4; ++nt)
                    acc[mt][nt] = __builtin_amdgcn_mfma_f32_16x16x32_bf16(
                        afr[mt], bcur[s][nt], acc[mt][nt], 0, 0, 0);
        }
        if (more) {
#pragma unroll
            for (int s = 0; s < 2; ++s)
#pragma unroll
                for (int nt = 0; nt < 4; ++nt) bcur[s][nt] = bnxt[s][nt];
        }
    }

    // epilogue: transpose through LDS, 16B coalesced stores
    __syncthreads();
    u16* ldsO = (u16*)smem;  // [128 px][136]
#pragma unroll
    for (int nt = 0; nt < 4; ++nt) {
        int co = co0 + wc * 64 + nt * 16 + r;
        float s = scale[co], bi = bias[co];
#pragma unroll
        for (int mt = 0; mt < 4; ++mt) {
#pragma unroll
            for (int i = 0; i < 4; ++i) {
                int p = wr * 64 + mt * 16 + q * 4 + i;
                ldsO[p * 136 + (wc * 64 + nt * 16 + r)] = f2bf(silu(acc[mt][nt][i] * s + bi));
            }
        }
    }
    __syncthreads();
#pragma unroll
    for (int rep = 0; rep < 8; ++rep) {
        int px = rep * 16 + (tid >> 4);
        int c8 = (tid & 15) * 8;
        *(v8u*)(out + ((size_t)n * 16384 + px0 + px) * Cout + co0 + c8) =
            *(const v8u*)&ldsO[px * 136 + c8];
    }
}

// ---------------------------------------------------------------------------
// cat_mfma v3: cv2 = 1x1 over implicit concat [t(256), y1, y2, y3] -> 256.
// Flat 10-chunk loop; B register double-buffer issued before staging.
// Output NCHW fp32 (float4 stores, already 16B).
// ---------------------------------------------------------------------------
__global__ __launch_bounds__(256) void cat_mfma(
    const u16* __restrict__ s0, const u16* __restrict__ s1,
    const u16* __restrict__ s2, const u16* __restrict__ s3,
    const u16* __restrict__ wt,  // [256][640]
    const float* __restrict__ scale, const float* __restrict__ bias,
    float* __restrict__ out) {
    __shared__ __align__(16) u16 lds[2][128][64];
    const int n = blockIdx.z, co0 = blockIdx.y * 128, px0 = blockIdx.x * 128;
    const int tid = threadIdx.x;
    const int lane = tid & 63, wv = tid >> 6;
    const int r = lane & 15, q = lane >> 4;
    const int wr = wv >> 1, wc = wv & 1;

    v4f acc[4][4];
#pragma unroll
    for (int a = 0; a < 4; ++a)
#pragma unroll
        for (int b = 0; b < 4; ++b) acc[a][b] = (v4f){0.f, 0.f, 0.f, 0.f};

    const u16* srcs[4] = {s0, s1, s2, s3};
    const int sCq[4] = {256, 128, 128, 128};
    const int kbq[4] = {0, 256, 384, 512};
    const int segs[10] = {0, 0, 0, 0, 1, 1, 2, 2, 3, 3};
    const int k0s[10] = {0, 64, 128, 192, 0, 64, 0, 64, 0, 64};

    auto stage = [&](int buf, int c) {
        int seg = segs[c]; int sc = sCq[seg]; int k0 = k0s[c];
        const u16* ab = srcs[seg] + ((size_t)n * 16384 + px0) * sc;
#pragma unroll
        for (int j = 0; j < 4; ++j) {
            int o = j * 4096 + tid * 16;
            int s2 = o ^ ((o >> 3) & 0x70);
            int px = s2 >> 7, cb = s2 & 127;
            gld16((const char*)(ab + (size_t)px * sc + k0) + cb,
                  (char*)&lds[buf][0][0] + j * 4096 + wv * 1024);
        }
    };
    auto loadB = [&](v8bf (&B)[2][4], int c) {
        const u16* wrow = wt + (size_t)(co0 + wc * 64 + r) * 640 + kbq[segs[c]] + k0s[c] + q * 8;
#pragma unroll
        for (int s = 0; s < 2; ++s)
#pragma unroll
            for (int nt = 0; nt < 4; ++nt)
                B[s][nt] = __builtin_bit_cast(v8bf,
                    *(const v8s*)(wrow + s * 32 + (size_t)nt * 16 * 640));
    };

    v8bf bcur[2][4], bnxt[2][4];
    loadB(bcur, 0);
    stage(0, 0);
    int buf = 0;
#pragma unroll
    for (int c = 0; c < 10; ++c, buf ^= 1) {
        __syncthreads();
        if (c < 9) {
            loadB(bnxt, c + 1);
            stage(buf ^ 1, c + 1);
        }
#pragma unroll
        for (int s = 0; s < 2; ++s) {
            v8bf afr[4];
#pragma unroll
            for (int mt = 0; mt < 4; ++mt) {
                int ba = (wr * 64 + mt * 16 + r) * 128 + s * 64 + q * 16;
                ba ^= (ba >> 3) & 0x70;
                afr[mt] = __builtin_bit_cast(v8bf,
                    *(const v8s*)((const char*)&lds[buf][0][0] + ba));
            }
#pragma unroll
            for (int mt = 0; mt < 4; ++mt)
#pragma unroll
                for (int nt = 0; nt < 4; ++nt)
                    acc[mt][nt] = __builtin_amdgcn_mfma_f32_16x16x32_bf16(
                        afr[mt], bcur[s][nt], acc[mt][nt], 0, 0, 0);
        }
        if (c < 9) {
#pragma unroll
            for (int s = 0; s < 2; ++s)
#pragma unroll
                for (int nt = 0; nt < 4; ++nt) bcur[s][nt] = bnxt[s][nt];
        }
    }

#pragma unroll
    for (int nt = 0; nt < 4; ++nt) {
        int co = co0 + wc * 64 + nt * 16 + r;
        float s = scale[co], bi = bias[co];
#pragma unroll
        for (int mt = 0; mt < 4; ++mt) {
            int p = px0 + wr * 64 + mt * 16 + q * 4;
            v4f o;
#pragma unroll
            for (int i = 0; i < 4; ++i) o[i] = silu(acc[mt][nt][i] * s + bi);
            *(v4f*)(out + (size_t)(n * 256 + co) * 16384 + p) = o;
        }
    }
}

// ---------------------------------------------------------------------------
// Generic MFMA conv (kept for cvm2/cvm3 strided taps; minor cost)
// ---------------------------------------------------------------------------
template <int KH, int KW, int S, int PAD, int CIN>
__global__ __launch_bounds__(256) void conv_mfma(
    const u16* __restrict__ src, int c0, int srcC,
    const u16* __restrict__ wt,
    const float* __restrict__ scale, const float* __restrict__ bias,
    u16* __restrict__ out, int Hin, int Win, int Wout, int Cout) {
    const int n = blockIdx.z;
    const int co0 = blockIdx.y * 64;
    const int hw0 = blockIdx.x * 64;
    const int tid = threadIdx.x;
    const int lane = tid & 63, wv = tid >> 6;
    const int r = lane & 15, q = lane >> 4;
    const int wr = wv >> 1, wc = wv & 1;

    const int m0 = hw0 + wr * 32 + r;
    const int m1 = m0 + 16;
    const int h0 = m0 / Wout, w0 = m0 - h0 * Wout;
    const int h1 = m1 / Wout, w1 = m1 - h1 * Wout;

    v4f acc00 = {0.f, 0.f, 0.f, 0.f}, acc01 = {0.f, 0.f, 0.f, 0.f};
    v4f acc10 = {0.f, 0.f, 0.f, 0.f}, acc11 = {0.f, 0.f, 0.f, 0.f};

    const u16* b0base = wt + (size_t)(co0 + wc * 32 + r) * CIN + q * 8;
    const size_t wtap = (size_t)Cout * CIN;

    int tap = 0;
#pragma unroll
    for (int kh = 0; kh < KH; ++kh)
#pragma unroll
        for (int kw = 0; kw < KW; ++kw, ++tap) {
            int ih0 = h0 * S + kh - PAD, iw0 = w0 * S + kw - PAD;
            int ih1 = h1 * S + kh - PAD, iw1 = w1 * S + kw - PAD;
            bool v0 = ((unsigned)ih0 < (unsigned)Hin) & ((unsigned)iw0 < (unsigned)Win);
            bool v1 = ((unsigned)ih1 < (unsigned)Hin) & ((unsigned)iw1 < (unsigned)Win);
            int p0i = v0 ? (n * Hin + ih0) * Win + iw0 : 0;
            int p1i = v1 ? (n * Hin + ih1) * Win + iw1 : 0;
            const u16* a0 = src + (size_t)p0i * srcC + c0 + q * 8;
            const u16* a1 = src + (size_t)p1i * srcC + c0 + q * 8;
            const u16* b0 = b0base + (size_t)tap * wtap;
            const u16* b1 = b0 + (size_t)16 * CIN;
#pragma unroll
            for (int k = 0; k < CIN; k += 32) {
                v8s za = {0, 0, 0, 0, 0, 0, 0, 0};
                v8s a0s = za, a1s = za;
                if (v0) a0s = *(const v8s*)(a0 + k);
                if (v1) a1s = *(const v8s*)(a1 + k);
                v8s b0s = *(const v8s*)(b0 + k);
                v8s b1s = *(const v8s*)(b1 + k);
                v8bf af0 = __builtin_bit_cast(v8bf, a0s);
                v8bf af1 = __builtin_bit_cast(v8bf, a1s);
                v8bf bw0 = __builtin_bit_cast(v8bf, b0s);
                v8bf bw1 = __builtin_bit_cast(v8bf, b1s);
                acc00 = __builtin_amdgcn_mfma_f32_16x16x32_bf16(af0, bw0, acc00, 0, 0, 0);
                acc01 = __builtin_amdgcn_mfma_f32_16x16x32_bf16(af0, bw1, acc01, 0, 0, 0);
                acc10 = __builtin_amdgcn_mfma_f32_16x16x32_bf16(af1, bw0, acc10, 0, 0, 0);
                acc11 = __builtin_amdgcn_mfma_f32_16x16x32_bf16(af1, bw1, acc11, 0, 0, 0);
            }
        }

    const int HWo = gridDim.x * 64;
#pragma unroll
    for (int ct = 0; ct < 2; ++ct) {
        v4f av0 = ct ? acc01 : acc00;
        v4f av1 = ct ? acc11 : acc10;
        int co = co0 + wc * 32 + ct * 16 + r;
        float s = scale[co], bb = bias[co];
        int mb = hw0 + wr * 32 + q * 4;
#pragma unroll
        for (int i = 0; i < 4; ++i) {
            float x0 = av0[i] * s + bb;
            float x1 = av1[i] * s + bb;
            out[((size_t)n * HWo + mb + i) * Cout + co] = f2bf(silu(x0));
            out[((size_t)n * HWo + mb + 16 + i) * Cout + co] = f2bf(silu(x1));
        }
    }
}

// ---------------------------------------------------------------------------
// u2 carafe == nearest 2x upsample (+ residual y1). NHWC bf16, C=128.
// ---------------------------------------------------------------------------
__global__ __launch_bounds__(256) void k_upadd(const u16* __restrict__ y2a,
                                               const u16* __restrict__ y1,
                                               u16* __restrict__ out) {
    int t = blockIdx.x * 256 + threadIdx.x;  // 2,097,152
    int cg = t & 15; int pix = t >> 4;
    int n = pix >> 14; int p = pix & 16383; int ho = p >> 7; int wo = p & 127;
    const u16* a = y2a + ((size_t)((n * 64 + (ho >> 1)) * 64 + (wo >> 1))) * 128 + cg * 8;
    const u16* b = y1 + (size_t)pix * 128 + cg * 8;
    v8s av = *(const v8s*)a;
    v8s bv = *(const v8s*)b;
    v8u o;
#pragma unroll
    for (int e = 0; e < 8; ++e) o[e] = f2bf(bf2f((u16)av[e]) + bf2f((u16)bv[e]));
    *(v8u*)(out + (size_t)pix * 128 + cg * 8) = o;
}

// ---------------------------------------------------------------------------
// u3 carafe pieces (small spatial, scalar fp32 math)
// ---------------------------------------------------------------------------
__global__ __launch_bounds__(256) void k_u3down(const u16* __restrict__ y3a,
                                                const float* __restrict__ w,
                                                const float* __restrict__ b,
                                                float* __restrict__ ktA) {
    int t = blockIdx.x * 256 + threadIdx.x;  // 262,144
    int co = t & 31; int pix = t >> 5;
    const u16* xr = y3a + (size_t)pix * 128;
    const float* wr = w + (size_t)co * 128;
    float acc = b[co];
#pragma unroll 16
    for (int k = 0; k < 128; ++k) acc += bf2f(xr[k]) * wr[k];
    ktA[t] = acc;
}

__global__ __launch_bounds__(256) void k_u3enc(const float* __restrict__ ktA,
                                               const float* __restrict__ ew,
                                               const float* __restrict__ eb,
                                               float* __restrict__ wtsm) {
    int t = blockIdx.x * 256 + threadIdx.x;  // 131,072
    int r = t & 15; int pix = t >> 4;
    int n = pix >> 10; int hw = pix & 1023; int h = hw >> 5; int w = hw & 31;
    float v[4];
#pragma unroll
    for (int kk = 0; kk < 4; ++kk) {
        int co = kk * 16 + r;
        float acc = eb[co];
#pragma unroll
        for (int dh = 0; dh < 2; ++dh)
#pragma unroll
            for (int dw = 0; dw < 2; ++dw) {
                int hh = h - 1 + dh, ww = w - 1 + dw;
                if (hh < 0 || ww < 0) continue;
                const float* kp = ktA + ((size_t)((n * 32 + hh) * 32 + ww)) * 32;
                const float* wp = ew + (size_t)co * 128 + dh * 2 + dw;
                for (int ci = 0; ci < 32; ++ci) acc += kp[ci] * wp[ci * 4];
            }
        v[kk] = acc;
    }
    float mx = fmaxf(fmaxf(v[0], v[1]), fmaxf(v[2], v[3]));
    float e0 = __expf(v[0] - mx), e1 = __expf(v[1] - mx), e2 = __expf(v[2] - mx), e3 = __expf(v[3] - mx);
    float inv = 1.f / (e0 + e1 + e2 + e3);
    float* o = wtsm + (size_t)t * 4;
    o[0] = e0 * inv; o[1] = e1 * inv; o[2] = e2 * inv; o[3] = e3 * inv;
}

__global__ __launch_bounds__(256) void k_carafe(const u16* __restrict__ y3a,
                                                const float* __restrict__ wtsm,
                                                const u16* __restrict__ y2,
                                                u16* __restrict__ out) {
    int t = blockIdx.x * 256 + threadIdx.x;  // 2,097,152
    int cg = t & 15; int pix = t >> 4;
    int n = pix >> 14; int p = pix & 16383; int ho = p >> 7; int wo = p & 127;
    int h = ho >> 2, i = ho & 3, w = wo >> 2, j = wo & 3, r = i * 4 + j;
    const float* wv = wtsm + ((size_t)((n * 1024 + h * 32 + w) * 16 + r)) * 4;
    v8s yv = *(const v8s*)(y2 + (size_t)pix * 128 + cg * 8);
    float acc[8];
#pragma unroll
    for (int e = 0; e < 8; ++e) acc[e] = bf2f((u16)yv[e]);
#pragma unroll
    for (int kk = 0; kk < 4; ++kk) {
        int ki = kk >> 1, kj = kk & 1;
        int hh = h + ki - 1, ww = w + kj - 1;
        if (hh < 0 || ww < 0) continue;
        float wk = wv[kk];
        v8s sv = *(const v8s*)(y3a + ((size_t)((n * 32 + hh) * 32 + ww)) * 128 + cg * 8);
#pragma unroll
        for (int e = 0; e < 8; ++e) acc[e] += wk * bf2f((u16)sv[e]);
    }
    v8u o;
#pragma unroll
    for (int e = 0; e < 8; ++e) o[e] = f2bf(acc[e]);
    *(v8u*)(out + (size_t)pix * 128 + cg * 8) = o;
}

// ---------------------------------------------------------------------------
extern "C" void kernel_launch(void* const* d_in, const int* in_sizes, int n_in,
                              void* d_out, int out_size, void* d_ws, size_t ws_size,
                              hipStream_t stream) {
    const float* x     = (const float*)d_in[0];
    const float* cv1_w = (const float*)d_in[1];
    const float* cv1_s = (const float*)d_in[2];
    const float* cv1_b = (const float*)d_in[3];
    const float* m1a_w = (const float*)d_in[4];
    const float* m1a_s = (const float*)d_in[5];
    const float* m1a_b = (const float*)d_in[6];
    const float* m1b_w = (const float*)d_in[7];
    const float* m1b_s = (const float*)d_in[8];
    const float* m1b_b = (const float*)d_in[9];
    const float* m2a_w = (const float*)d_in[10];
    const float* m2a_s = (const float*)d_in[11];
    const float* m2a_b = (const float*)d_in[12];
    const float* m2b_w = (const float*)d_in[13];
    const float* m2b_s = (const float*)d_in[14];
    const float* m2b_b = (const float*)d_in[15];
    const float* m3a_w = (const float*)d_in[16];
    const float* m3a_s = (const float*)d_in[17];
    const float* m3a_b = (const float*)d_in[18];
    const float* m3b_w = (const float*)d_in[19];
    const float* m3b_s = (const float*)d_in[20];
    const float* m3b_b = (const float*)d_in[21];
    const float* cvm2_w = (const float*)d_in[22];
    const float* cvm2_s = (const float*)d_in[23];
    const float* cvm2_b = (const float*)d_in[24];
    const float* cvm3_w = (const float*)d_in[25];
    const float* cvm3_s = (const float*)d_in[26];
    const float* cvm3_b = (const float*)d_in[27];
    // d_in[28..31]: u2_down_w/b, u2_enc_w/b — dead (k=1 softmax == 1)
    const float* u3_down_w = (const float*)d_in[32];
    const float* u3_down_b = (const float*)d_in[33];
    const float* u3_enc_w  = (const float*)d_in[34];
    const float* u3_enc_b  = (const float*)d_in[35];
    const float* cv2_w = (const float*)d_in[36];
    const float* cv2_s = (const float*)d_in[37];
    const float* cv2_b = (const float*)d_in[38];

    char* ws = (char*)d_ws;
    u16* A    = (u16*)(ws + 0);          // x_nhwc (67MB); later y2/y3
    u16* t    = (u16*)(ws + 67108864);   // 67MB
    u16* y1   = (u16*)(ws + 134217728);  // 33.5MB
    u16* bt   = (u16*)(ws + 167772160);  // 33.5MB bneck tmp
    u16* te   = (u16*)(ws + 201326592);  // 33.5MB y2b / y3b
    u16* y2a  = (u16*)(ws + 234881024);  // 8.4MB
    u16* y3a  = (u16*)(ws + 243269632);  // 2.1MB
    float* ktA = (float*)(ws + 245366784);  // 1MB fp32
    float* wts = (float*)(ws + 246415360);  // 2MB fp32
    u16* w3t  = (u16*)(ws + 248512512);  // 6 x 147456 bf16
    u16* wu2  = (u16*)(ws + 250281984);  // 65536 bf16
    u16* wu4  = (u16*)(ws + 250413056);  // 262144 bf16
    u16* wc1  = (u16*)(ws + 250937344);  // 65536 bf16
    u16* wc2  = (u16*)(ws + 251068416);  // 163840 bf16
    u16* y2 = A;
    u16* y3 = A + 16777216;

    dim3 B(256);
    // weight conversions / reshuffles
    wtrans3<<<576, B, 0, stream>>>(m1a_w, w3t + 0 * 147456);
    wtrans3<<<576, B, 0, stream>>>(m1b_w, w3t + 1 * 147456);
    wtrans3<<<576, B, 0, stream>>>(m2a_w, w3t + 2 * 147456);
    wtrans3<<<576, B, 0, stream>>>(m2b_w, w3t + 3 * 147456);
    wtrans3<<<576, B, 0, stream>>>(m3a_w, w3t + 4 * 147456);
    wtrans3<<<576, B, 0, stream>>>(m3b_w, w3t + 5 * 147456);
    wtrans_ps<<<256, B, 0, stream>>>(cvm2_w, wu2, 4);
    wtrans_ps<<<1024, B, 0, stream>>>(cvm3_w, wu4, 16);
    cvtw<<<256, B, 0, stream>>>(cv1_w, wc1, 65536);
    cvtw<<<640, B, 0, stream>>>(cv2_w, wc2, 163840);

    // x -> NHWC bf16
    nchw2nhwc<<<dim3(256, 4, 8), B, 0, stream>>>(x, A);

    // cv1 (1x1 256->256) -> t  (y = ch 0..127, y0 = ch 128..255)
    conv1_mfma<<<dim3(128, 2, 8), B, 0, stream>>>(A, 256, wc1, cv1_s, cv1_b, t, 256);

    // bneck1: y0 -> bt -> y1
    conv3_mfma<<<dim3(256, 8), B, 0, stream>>>(t, 128, 256, w3t + 0 * 147456, m1a_s, m1a_b, bt);
    conv3_mfma<<<dim3(256, 8), B, 0, stream>>>(bt, 0, 128, w3t + 1 * 147456, m1b_s, m1b_b, y1);

    // cvm2: pixel_unshuffle(y1,2) + 1x1 == 2x2/stride2 conv -> y2a (64x64)
    conv_mfma<2, 2, 2, 0, 128><<<dim3(64, 2, 8), B, 0, stream>>>(
        y1, 0, 128, wu2, cvm2_s, cvm2_b, y2a, 128, 128, 64, 128);

    // u2 carafe == nearest 2x upsample, + y1 -> te
    k_upadd<<<8192, B, 0, stream>>>(y2a, y1, te);

    // bneck2: te -> bt -> y2
    conv3_mfma<<<dim3(256, 8), B, 0, stream>>>(te, 0, 128, w3t + 2 * 147456, m2a_s, m2a_b, bt);
    conv3_mfma<<<dim3(256, 8), B, 0, stream>>>(bt, 0, 128, w3t + 3 * 147456, m2b_s, m2b_b, y2);

    // cvm3: pixel_unshuffle(y2,4) + 1x1 == 4x4/stride4 conv -> y3a (32x32)
    conv_mfma<4, 4, 4, 0, 128><<<dim3(16, 2, 8), B, 0, stream>>>(
        y2, 0, 128, wu4, cvm3_s, cvm3_b, y3a, 128, 128, 32, 128);

    // u3 carafe (k=2, up=4)
    k_u3down<<<1024, B, 0, stream>>>(y3a, u3_down_w, u3_down_b, ktA);
    k_u3enc<<<512, B, 0, stream>>>(ktA, u3_enc_w, u3_enc_b, wts);
    k_carafe<<<8192, B, 0, stream>>>(y3a, wts, y2, te);

    // bneck3: te -> bt -> y3
    conv3_mfma<<<dim3(256, 8), B, 0, stream>>>(te, 0, 128, w3t + 4 * 147456, m3a_s, m3a_b, bt);
    conv3_mfma<<<dim3(256, 8), B, 0, stream>>>(bt, 0, 128, w3t + 5 * 147456, m3b_s, m3b_b, y3);

    // cv2: 1x1 over concat [t, y1, y2, y3] -> d_out (NCHW fp32)
    cat_mfma<<<dim3(128, 2, 8), B, 0, stream>>>(t, y1, y2, y3, wc2, cv2_s, cv2_b, (float*)d_out);
}

// Round 4
// 1171.086 us; speedup vs baseline: 1.1850x; 1.1760x over previous
//
#include <hip/hip_runtime.h>

typedef unsigned short u16;
typedef short v8s __attribute__((ext_vector_type(8)));
typedef u16 v8u __attribute__((ext_vector_type(8)));
typedef float v4f __attribute__((ext_vector_type(4)));
typedef __bf16 v8bf __attribute__((ext_vector_type(8)));

__device__ __forceinline__ float bf2f(u16 u) {
    unsigned x = ((unsigned)u) << 16; float f; __builtin_memcpy(&f, &x, 4); return f;
}
__device__ __forceinline__ u16 f2bf(float f) {
    unsigned x; __builtin_memcpy(&x, &f, 4);
    x = x + 0x7FFFu + ((x >> 16) & 1u);
    return (u16)(x >> 16);
}
__device__ __forceinline__ float silu(float v) { return v / (1.f + __expf(-v)); }

// async global->LDS 16B per lane; l must be wave-uniform, data lands at l+lane*16
__device__ __forceinline__ void gld16(const void* g, void* l) {
    __builtin_amdgcn_global_load_lds(
        (const __attribute__((address_space(1))) unsigned int*)(uintptr_t)g,
        (__attribute__((address_space(3))) unsigned int*)(unsigned int)(uintptr_t)l,
        16, 0, 0);
}

// ---------------------------------------------------------------------------
// Weight conversion / reshuffle kernels (fp32 in -> bf16 out)
// ---------------------------------------------------------------------------
__global__ void cvtw(const float* __restrict__ in, u16* __restrict__ out, int n) {
    int i = blockIdx.x * 256 + threadIdx.x;
    if (i < n) out[i] = f2bf(in[i]);
}
// 3x3: in[co][ci][tap(9)] -> out[tap][co][ci]   (128x128x9)
__global__ void wtrans3(const float* __restrict__ in, u16* __restrict__ out) {
    int i = blockIdx.x * 256 + threadIdx.x;
    if (i >= 147456) return;
    int tap = i % 9; int rem = i / 9; int ci = rem & 127; int co = rem >> 7;
    out[((tap * 128 + co) << 7) + ci] = f2bf(in[i]);
}
// pixel-unshuffle 1x1: in[co][c*R2+tap] -> out[tap][co][c]  (co=128, c=128)
__global__ void wtrans_ps(const float* __restrict__ in, u16* __restrict__ out, int R2) {
    int i = blockIdx.x * 256 + threadIdx.x;
    int tap = i % R2; int rem = i / R2; int c = rem & 127; int co = rem >> 7;
    out[((tap * 128 + co) << 7) + c] = f2bf(in[i]);
}

// ---------------------------------------------------------------------------
// NCHW fp32 -> NHWC bf16 transpose for x (C=256, HW=16384)
// ---------------------------------------------------------------------------
__global__ __launch_bounds__(256) void nchw2nhwc(const float* __restrict__ in, u16* __restrict__ out) {
    __shared__ u16 tile[64][72];
    const int n = blockIdx.z, c0 = blockIdx.y * 64, p0 = blockIdx.x * 64;
#pragma unroll
    for (int rep = 0; rep < 16; ++rep) {
        int idx = rep * 256 + threadIdx.x;
        int c = idx >> 6, p = idx & 63;
        tile[c][p] = f2bf(in[((size_t)(n * 256 + c0 + c)) * 16384 + p0 + p]);
    }
    __syncthreads();
#pragma unroll
    for (int rep = 0; rep < 16; ++rep) {
        int idx = rep * 256 + threadIdx.x;
        int p = idx >> 6, c = idx & 63;
        out[((size_t)n * 16384 + p0 + p) * 256 + c0 + c] = tile[c][p];
    }
}

// ---------------------------------------------------------------------------
// conv3_mfma v5: 3x3 s1 p1, Cin=128 (slice c0 of srcC), Cout=128, H=W=128.
// M=256 tile: block = 2 output rows x 128px x 64co, 4 waves; wave (wr,wc) =
// output row h0+wr x 32co; acc[8][2]=64 f32.
// Why: v2-v4 all pinned at ~115us because compute-per-barrier (72 MFMA,
// ~1400cy) < stage latency (~900cy) -> every __syncthreads (vmcnt(0) drain)
// re-exposed the staging. Now a chunk = 4 input rows x 128px x 32ci (32KB),
// 288 MFMA/wave (~5600cy) >> 900cy -> prefetch fully hidden.
// - double buffer 2x32KB = 64KB LDS -> 2 blocks/CU
// - each wave stages exactly one input row (wave-uniform gld16 dest)
// - 18 B frags loaded BEFORE stage(next): counted-vmcnt, never drains staging
// - XOR involution per 8KB row-block (store-side pre-swizzled source)
// - XCD banding: bx&7 = XCD, 8 tiles (16 rows) per XCD, co-twin same XCD
// - LDS-transpose epilogue -> 16B coalesced stores
// grid: (128, 8) = (64 tiles x 2 co-halves, n)
// ---------------------------------------------------------------------------
__global__ __launch_bounds__(256, 2) void conv3_mfma(
    const u16* __restrict__ src, int c0, int srcC,
    const u16* __restrict__ wt,  // [9][128][128]
    const float* __restrict__ scale, const float* __restrict__ bias,
    u16* __restrict__ out) {
    __shared__ __align__(16) char smem[65536];  // 2 x 32KB stage / 36KB epilogue
    const int bx = blockIdx.x, n = blockIdx.y;
    const int tile = ((bx & 7) << 3) | (bx >> 4);   // 0..63, 8 tiles per XCD
    const int co0 = ((bx >> 3) & 1) * 64;
    const int h0 = tile * 2;
    const int tid = threadIdx.x;
    const int lane = tid & 63, wv = tid >> 6;
    const int r = lane & 15, q = lane >> 4;
    const int wr = wv >> 1, wc = wv & 1;   // wr = output row, wc = co 32-half

    v4f acc[8][2];
#pragma unroll
    for (int a = 0; a < 8; ++a)
#pragma unroll
        for (int b = 0; b < 2; ++b) acc[a][b] = (v4f){0.f, 0.f, 0.f, 0.f};

    const size_t rowstride = (size_t)128 * srcC;  // u16 units
    const u16* nbase = src + (size_t)n * 128 * rowstride + c0;

    // stage one 32ci chunk: [4 input rows][128px][32ci] = 32 x 1KB.
    // wave wv stages input row (h0-1+wv): slots t = wv*8 .. wv*8+7.
    // Within the 8KB row-block, LDS[l] = G[sw(l)], sw = l ^ ((l>>3)&0x70).
    auto stage = [&](int buf, int k0) {
        const int hh = h0 - 1 + wv;              // wave-uniform
        char* base = smem + buf * 32768 + wv * 8192;
        if ((unsigned)hh < 128u) {
            const u16* g = nbase + (size_t)hh * rowstride + k0;
#pragma unroll
            for (int j = 0; j < 8; ++j) {
                int l = (j << 10) + lane * 16;   // linear byte off in 8KB row
                int sw = l ^ ((l >> 3) & 0x70);  // involution
                int px = sw >> 6, cb = sw & 63;
                gld16((const char*)(g + (size_t)px * srcC) + cb, base + (j << 10));
            }
        } else {
#pragma unroll
            for (int j = 0; j < 8; ++j)
                *(v8s*)(base + (j << 10) + lane * 16) = (v8s){0, 0, 0, 0, 0, 0, 0, 0};
        }
    };

    stage(0, 0);
    int buf = 0;
#pragma unroll
    for (int ch = 0; ch < 4; ++ch, buf ^= 1) {
        const int k0 = ch * 32;
        __syncthreads();  // drains vmcnt -> lds[buf] valid; buf^1 free to fill

        // all 18 B frags BEFORE stage(next): counted vmcnt leaves staging flying
        v8bf bfr[9][2];
#pragma unroll
        for (int tap = 0; tap < 9; ++tap)
#pragma unroll
            for (int nt = 0; nt < 2; ++nt)
                bfr[tap][nt] = __builtin_bit_cast(v8bf, *(const v8s*)(
                    wt + (size_t)((tap * 128 + co0 + wc * 32 + nt * 16 + r) << 7)
                       + k0 + q * 8));

        if (ch < 3) stage(buf ^ 1, k0 + 32);

        const char* abase = smem + buf * 32768;
#pragma unroll
        for (int tap = 0; tap < 9; ++tap) {
            const int kh = tap / 3, kw = tap % 3;
            const char* rbase = abase + ((wr + kh) << 13);  // input row wr+kh
#pragma unroll
            for (int mt = 0; mt < 8; ++mt) {
                int p = mt * 16 + r + kw - 1;        // px within the row
                bool vp = (unsigned)p < 128u;
                int pc = vp ? p : 0;
                int b = (pc << 6) + q * 16;
                b ^= (b >> 3) & 0x70;                // same involution
                v8s av = *(const v8s*)(rbase + b);
                if (!vp) av = (v8s){0, 0, 0, 0, 0, 0, 0, 0};
                v8bf af = __builtin_bit_cast(v8bf, av);
#pragma unroll
                for (int nt = 0; nt < 2; ++nt)
                    acc[mt][nt] = __builtin_amdgcn_mfma_f32_16x16x32_bf16(
                        af, bfr[tap][nt], acc[mt][nt], 0, 0, 0);
            }
        }
    }

    // epilogue: transpose through LDS ([256 px][72]), 16B coalesced stores
    __syncthreads();
    u16* ldsO = (u16*)smem;
#pragma unroll
    for (int nt = 0; nt < 2; ++nt) {
        int coL = wc * 32 + nt * 16 + r;
        int co = co0 + coL;
        float s = scale[co], bi = bias[co];
#pragma unroll
        for (int mt = 0; mt < 8; ++mt) {
#pragma unroll
            for (int i = 0; i < 4; ++i) {
                int p = wr * 128 + mt * 16 + q * 4 + i;
                ldsO[p * 72 + coL] = f2bf(silu(acc[mt][nt][i] * s + bi));
            }
        }
    }
    __syncthreads();
    const size_t obase = (size_t)n * 16384 + (size_t)h0 * 128;  // px index
#pragma unroll
    for (int rep = 0; rep < 8; ++rep) {
        int px = rep * 32 + (tid >> 3);     // 0..255 (2 rows contiguous NHWC)
        int c8 = (tid & 7) * 8;
        *(v8u*)(out + (obase + px) * 128 + co0 + c8) = *(const v8u*)&ldsO[px * 72 + c8];
    }
}

// ---------------------------------------------------------------------------
// conv1_mfma v3: 1x1 conv, K=srcC, output NHWC bf16. Block 128px x 128co.
// ---------------------------------------------------------------------------
__global__ __launch_bounds__(256) void conv1_mfma(
    const u16* __restrict__ src, int srcC,
    const u16* __restrict__ wt,  // [Cout][srcC]
    const float* __restrict__ scale, const float* __restrict__ bias,
    u16* __restrict__ out, int Cout) {
    __shared__ __align__(16) char smem[34816];  // 2x16KB stage / 34.8KB epilogue
    const int n = blockIdx.z, co0 = blockIdx.y * 128, px0 = blockIdx.x * 128;
    const int tid = threadIdx.x;
    const int lane = tid & 63, wv = tid >> 6;
    const int r = lane & 15, q = lane >> 4;
    const int wr = wv >> 1, wc = wv & 1;

    v4f acc[4][4];
#pragma unroll
    for (int a = 0; a < 4; ++a)
#pragma unroll
        for (int b = 0; b < 4; ++b) acc[a][b] = (v4f){0.f, 0.f, 0.f, 0.f};

    const u16* abase = src + ((size_t)n * 16384 + px0) * srcC;

    auto stage = [&](int buf, int k0) {
#pragma unroll
        for (int j = 0; j < 4; ++j) {
            int o = j * 4096 + tid * 16;
            int s2 = o ^ ((o >> 3) & 0x70);
            int px = s2 >> 7, cb = s2 & 127;
            gld16((const char*)(abase + (size_t)px * srcC + k0) + cb,
                  smem + buf * 16384 + j * 4096 + wv * 1024);
        }
    };
    auto loadB = [&](v8bf (&B)[2][4], int k0) {
        const u16* wrow = wt + (size_t)(co0 + wc * 64 + r) * srcC + k0 + q * 8;
#pragma unroll
        for (int s = 0; s < 2; ++s)
#pragma unroll
            for (int nt = 0; nt < 4; ++nt)
                B[s][nt] = __builtin_bit_cast(v8bf,
                    *(const v8s*)(wrow + s * 32 + (size_t)nt * 16 * srcC));
    };

    v8bf bcur[2][4], bnxt[2][4];
    loadB(bcur, 0);   // issued before any staging -> short counted wait
    stage(0, 0);
    int buf = 0;
    for (int k0 = 0; k0 < srcC; k0 += 64, buf ^= 1) {
        __syncthreads();
        bool more = (k0 + 64 < srcC);
        if (more) {
            loadB(bnxt, k0 + 64);      // B first...
            stage(buf ^ 1, k0 + 64);   // ...then staging: B wait never drains it
        }
#pragma unroll
        for (int s = 0; s < 2; ++s) {
            v8bf afr[4];
#pragma unroll
            for (int mt = 0; mt < 4; ++mt) {
                int ba = buf * 16384 + (wr * 64 + mt * 16 + r) * 128 + s * 64 + q * 16;
                ba ^= (ba >> 3) & 0x70;
                afr[mt] = __builtin_bit_cast(v8bf, *(const v8s*)(smem + ba));
            }
#pragma unroll
            for (int mt = 0; mt < 4; ++mt)
#pragma unroll
                for (int nt = 0; nt < 4; ++nt)
                    acc[mt][nt] = __builtin_amdgcn_mfma_f32_16x16x32_bf16(
                        afr[mt], bcur[s][nt], acc[mt][nt], 0, 0, 0);
        }
        if (more) {
#pragma unroll
            for (int s = 0; s < 2; ++s)
#pragma unroll
                for (int nt = 0; nt < 4; ++nt) bcur[s][nt] = bnxt[s][nt];
        }
    }

    // epilogue: transpose through LDS, 16B coalesced stores
    __syncthreads();
    u16* ldsO = (u16*)smem;  // [128 px][136]
#pragma unroll
    for (int nt = 0; nt < 4; ++nt) {
        int co = co0 + wc * 64 + nt * 16 + r;
        float s = scale[co], bi = bias[co];
#pragma unroll
        for (int mt = 0; mt < 4; ++mt) {
#pragma unroll
            for (int i = 0; i < 4; ++i) {
                int p = wr * 64 + mt * 16 + q * 4 + i;
                ldsO[p * 136 + (wc * 64 + nt * 16 + r)] = f2bf(silu(acc[mt][nt][i] * s + bi));
            }
        }
    }
    __syncthreads();
#pragma unroll
    for (int rep = 0; rep < 8; ++rep) {
        int px = rep * 16 + (tid >> 4);
        int c8 = (tid & 15) * 8;
        *(v8u*)(out + ((size_t)n * 16384 + px0 + px) * Cout + co0 + c8) =
            *(const v8u*)&ldsO[px * 136 + c8];
    }
}

// ---------------------------------------------------------------------------
// cat_mfma v3: cv2 = 1x1 over implicit concat [t(256), y1, y2, y3] -> 256.
// ---------------------------------------------------------------------------
__global__ __launch_bounds__(256) void cat_mfma(
    const u16* __restrict__ s0, const u16* __restrict__ s1,
    const u16* __restrict__ s2, const u16* __restrict__ s3,
    const u16* __restrict__ wt,  // [256][640]
    const float* __restrict__ scale, const float* __restrict__ bias,
    float* __restrict__ out) {
    __shared__ __align__(16) u16 lds[2][128][64];
    const int n = blockIdx.z, co0 = blockIdx.y * 128, px0 = blockIdx.x * 128;
    const int tid = threadIdx.x;
    const int lane = tid & 63, wv = tid >> 6;
    const int r = lane & 15, q = lane >> 4;
    const int wr = wv >> 1, wc = wv & 1;

    v4f acc[4][4];
#pragma unroll
    for (int a = 0; a < 4; ++a)
#pragma unroll
        for (int b = 0; b < 4; ++b) acc[a][b] = (v4f){0.f, 0.f, 0.f, 0.f};

    const u16* srcs[4] = {s0, s1, s2, s3};
    const int sCq[4] = {256, 128, 128, 128};
    const int kbq[4] = {0, 256, 384, 512};
    const int segs[10] = {0, 0, 0, 0, 1, 1, 2, 2, 3, 3};
    const int k0s[10] = {0, 64, 128, 192, 0, 64, 0, 64, 0, 64};

    auto stage = [&](int buf, int c) {
        int seg = segs[c]; int sc = sCq[seg]; int k0 = k0s[c];
        const u16* ab = srcs[seg] + ((size_t)n * 16384 + px0) * sc;
#pragma unroll
        for (int j = 0; j < 4; ++j) {
            int o = j * 4096 + tid * 16;
            int s2 = o ^ ((o >> 3) & 0x70);
            int px = s2 >> 7, cb = s2 & 127;
            gld16((const char*)(ab + (size_t)px * sc + k0) + cb,
                  (char*)&lds[buf][0][0] + j * 4096 + wv * 1024);
        }
    };
    auto loadB = [&](v8bf (&B)[2][4], int c) {
        const u16* wrow = wt + (size_t)(co0 + wc * 64 + r) * 640 + kbq[segs[c]] + k0s[c] + q * 8;
#pragma unroll
        for (int s = 0; s < 2; ++s)
#pragma unroll
            for (int nt = 0; nt < 4; ++nt)
                B[s][nt] = __builtin_bit_cast(v8bf,
                    *(const v8s*)(wrow + s * 32 + (size_t)nt * 16 * 640));
    };

    v8bf bcur[2][4], bnxt[2][4];
    loadB(bcur, 0);
    stage(0, 0);
    int buf = 0;
#pragma unroll
    for (int c = 0; c < 10; ++c, buf ^= 1) {
        __syncthreads();
        if (c < 9) {
            loadB(bnxt, c + 1);
            stage(buf ^ 1, c + 1);
        }
#pragma unroll
        for (int s = 0; s < 2; ++s) {
            v8bf afr[4];
#pragma unroll
            for (int mt = 0; mt < 4; ++mt) {
                int ba = (wr * 64 + mt * 16 + r) * 128 + s * 64 + q * 16;
                ba ^= (ba >> 3) & 0x70;
                afr[mt] = __builtin_bit_cast(v8bf,
                    *(const v8s*)((const char*)&lds[buf][0][0] + ba));
            }
#pragma unroll
            for (int mt = 0; mt < 4; ++mt)
#pragma unroll
                for (int nt = 0; nt < 4; ++nt)
                    acc[mt][nt] = __builtin_amdgcn_mfma_f32_16x16x32_bf16(
                        afr[mt], bcur[s][nt], acc[mt][nt], 0, 0, 0);
        }
        if (c < 9) {
#pragma unroll
            for (int s = 0; s < 2; ++s)
#pragma unroll
                for (int nt = 0; nt < 4; ++nt) bcur[s][nt] = bnxt[s][nt];
        }
    }

#pragma unroll
    for (int nt = 0; nt < 4; ++nt) {
        int co = co0 + wc * 64 + nt * 16 + r;
        float s = scale[co], bi = bias[co];
#pragma unroll
        for (int mt = 0; mt < 4; ++mt) {
            int p = px0 + wr * 64 + mt * 16 + q * 4;
            v4f o;
#pragma unroll
            for (int i = 0; i < 4; ++i) o[i] = silu(acc[mt][nt][i] * s + bi);
            *(v4f*)(out + (size_t)(n * 256 + co) * 16384 + p) = o;
        }
    }
}

// ---------------------------------------------------------------------------
// Generic MFMA conv (kept for cvm2/cvm3 strided taps; minor cost)
// ---------------------------------------------------------------------------
template <int KH, int KW, int S, int PAD, int CIN>
__global__ __launch_bounds__(256) void conv_mfma(
    const u16* __restrict__ src, int c0, int srcC,
    const u16* __restrict__ wt,
    const float* __restrict__ scale, const float* __restrict__ bias,
    u16* __restrict__ out, int Hin, int Win, int Wout, int Cout) {
    const int n = blockIdx.z;
    const int co0 = blockIdx.y * 64;
    const int hw0 = blockIdx.x * 64;
    const int tid = threadIdx.x;
    const int lane = tid & 63, wv = tid >> 6;
    const int r = lane & 15, q = lane >> 4;
    const int wr = wv >> 1, wc = wv & 1;

    const int m0 = hw0 + wr * 32 + r;
    const int m1 = m0 + 16;
    const int h0 = m0 / Wout, w0 = m0 - h0 * Wout;
    const int h1 = m1 / Wout, w1 = m1 - h1 * Wout;

    v4f acc00 = {0.f, 0.f, 0.f, 0.f}, acc01 = {0.f, 0.f, 0.f, 0.f};
    v4f acc10 = {0.f, 0.f, 0.f, 0.f}, acc11 = {0.f, 0.f, 0.f, 0.f};

    const u16* b0base = wt + (size_t)(co0 + wc * 32 + r) * CIN + q * 8;
    const size_t wtap = (size_t)Cout * CIN;

    int tap = 0;
#pragma unroll
    for (int kh = 0; kh < KH; ++kh)
#pragma unroll
        for (int kw = 0; kw < KW; ++kw, ++tap) {
            int ih0 = h0 * S + kh - PAD, iw0 = w0 * S + kw - PAD;
            int ih1 = h1 * S + kh - PAD, iw1 = w1 * S + kw - PAD;
            bool v0 = ((unsigned)ih0 < (unsigned)Hin) & ((unsigned)iw0 < (unsigned)Win);
            bool v1 = ((unsigned)ih1 < (unsigned)Hin) & ((unsigned)iw1 < (unsigned)Win);
            int p0i = v0 ? (n * Hin + ih0) * Win + iw0 : 0;
            int p1i = v1 ? (n * Hin + ih1) * Win + iw1 : 0;
            const u16* a0 = src + (size_t)p0i * srcC + c0 + q * 8;
            const u16* a1 = src + (size_t)p1i * srcC + c0 + q * 8;
            const u16* b0 = b0base + (size_t)tap * wtap;
            const u16* b1 = b0 + (size_t)16 * CIN;
#pragma unroll
            for (int k = 0; k < CIN; k += 32) {
                v8s za = {0, 0, 0, 0, 0, 0, 0, 0};
                v8s a0s = za, a1s = za;
                if (v0) a0s = *(const v8s*)(a0 + k);
                if (v1) a1s = *(const v8s*)(a1 + k);
                v8s b0s = *(const v8s*)(b0 + k);
                v8s b1s = *(const v8s*)(b1 + k);
                v8bf af0 = __builtin_bit_cast(v8bf, a0s);
                v8bf af1 = __builtin_bit_cast(v8bf, a1s);
                v8bf bw0 = __builtin_bit_cast(v8bf, b0s);
                v8bf bw1 = __builtin_bit_cast(v8bf, b1s);
                acc00 = __builtin_amdgcn_mfma_f32_16x16x32_bf16(af0, bw0, acc00, 0, 0, 0);
                acc01 = __builtin_amdgcn_mfma_f32_16x16x32_bf16(af0, bw1, acc01, 0, 0, 0);
                acc10 = __builtin_amdgcn_mfma_f32_16x16x32_bf16(af1, bw0, acc10, 0, 0, 0);
                acc11 = __builtin_amdgcn_mfma_f32_16x16x32_bf16(af1, bw1, acc11, 0, 0, 0);
            }
        }

    const int HWo = gridDim.x * 64;
#pragma unroll
    for (int ct = 0; ct < 2; ++ct) {
        v4f av0 = ct ? acc01 : acc00;
        v4f av1 = ct ? acc11 : acc10;
        int co = co0 + wc * 32 + ct * 16 + r;
        float s = scale[co], bb = bias[co];
        int mb = hw0 + wr * 32 + q * 4;
#pragma unroll
        for (int i = 0; i < 4; ++i) {
            float x0 = av0[i] * s + bb;
            float x1 = av1[i] * s + bb;
            out[((size_t)n * HWo + mb + i) * Cout + co] = f2bf(silu(x0));
            out[((size_t)n * HWo + mb + 16 + i) * Cout + co] = f2bf(silu(x1));
        }
    }
}

// ---------------------------------------------------------------------------
// u2 carafe == nearest 2x upsample (+ residual y1). NHWC bf16, C=128.
// ---------------------------------------------------------------------------
__global__ __launch_bounds__(256) void k_upadd(const u16* __restrict__ y2a,
                                               const u16* __restrict__ y1,
                                               u16* __restrict__ out) {
    int t = blockIdx.x * 256 + threadIdx.x;  // 2,097,152
    int cg = t & 15; int pix = t >> 4;
    int n = pix >> 14; int p = pix & 16383; int ho = p >> 7; int wo = p & 127;
    const u16* a = y2a + ((size_t)((n * 64 + (ho >> 1)) * 64 + (wo >> 1))) * 128 + cg * 8;
    const u16* b = y1 + (size_t)pix * 128 + cg * 8;
    v8s av = *(const v8s*)a;
    v8s bv = *(const v8s*)b;
    v8u o;
#pragma unroll
    for (int e = 0; e < 8; ++e) o[e] = f2bf(bf2f((u16)av[e]) + bf2f((u16)bv[e]));
    *(v8u*)(out + (size_t)pix * 128 + cg * 8) = o;
}

// ---------------------------------------------------------------------------
// u3 carafe pieces (small spatial, scalar fp32 math)
// ---------------------------------------------------------------------------
__global__ __launch_bounds__(256) void k_u3down(const u16* __restrict__ y3a,
                                                const float* __restrict__ w,
                                                const float* __restrict__ b,
                                                float* __restrict__ ktA) {
    int t = blockIdx.x * 256 + threadIdx.x;  // 262,144
    int co = t & 31; int pix = t >> 5;
    const u16* xr = y3a + (size_t)pix * 128;
    const float* wr = w + (size_t)co * 128;
    float acc = b[co];
#pragma unroll 16
    for (int k = 0; k < 128; ++k) acc += bf2f(xr[k]) * wr[k];
    ktA[t] = acc;
}

__global__ __launch_bounds__(256) void k_u3enc(const float* __restrict__ ktA,
                                               const float* __restrict__ ew,
                                               const float* __restrict__ eb,
                                               float* __restrict__ wtsm) {
    int t = blockIdx.x * 256 + threadIdx.x;  // 131,072
    int r = t & 15; int pix = t >> 4;
    int n = pix >> 10; int hw = pix & 1023; int h = hw >> 5; int w = hw & 31;
    float v[4];
#pragma unroll
    for (int kk = 0; kk < 4; ++kk) {
        int co = kk * 16 + r;
        float acc = eb[co];
#pragma unroll
        for (int dh = 0; dh < 2; ++dh)
#pragma unroll
            for (int dw = 0; dw < 2; ++dw) {
                int hh = h - 1 + dh, ww = w - 1 + dw;
                if (hh < 0 || ww < 0) continue;
                const float* kp = ktA + ((size_t)((n * 32 + hh) * 32 + ww)) * 32;
                const float* wp = ew + (size_t)co * 128 + dh * 2 + dw;
                for (int ci = 0; ci < 32; ++ci) acc += kp[ci] * wp[ci * 4];
            }
        v[kk] = acc;
    }
    float mx = fmaxf(fmaxf(v[0], v[1]), fmaxf(v[2], v[3]));
    float e0 = __expf(v[0] - mx), e1 = __expf(v[1] - mx), e2 = __expf(v[2] - mx), e3 = __expf(v[3] - mx);
    float inv = 1.f / (e0 + e1 + e2 + e3);
    float* o = wtsm + (size_t)t * 4;
    o[0] = e0 * inv; o[1] = e1 * inv; o[2] = e2 * inv; o[3] = e3 * inv;
}

__global__ __launch_bounds__(256) void k_carafe(const u16* __restrict__ y3a,
                                                const float* __restrict__ wtsm,
                                                const u16* __restrict__ y2,
                                                u16* __restrict__ out) {
    int t = blockIdx.x * 256 + threadIdx.x;  // 2,097,152
    int cg = t & 15; int pix = t >> 4;
    int n = pix >> 14; int p = pix & 16383; int ho = p >> 7; int wo = p & 127;
    int h = ho >> 2, i = ho & 3, w = wo >> 2, j = wo & 3, r = i * 4 + j;
    const float* wv = wtsm + ((size_t)((n * 1024 + h * 32 + w) * 16 + r)) * 4;
    v8s yv = *(const v8s*)(y2 + (size_t)pix * 128 + cg * 8);
    float acc[8];
#pragma unroll
    for (int e = 0; e < 8; ++e) acc[e] = bf2f((u16)yv[e]);
#pragma unroll
    for (int kk = 0; kk < 4; ++kk) {
        int ki = kk >> 1, kj = kk & 1;
        int hh = h + ki - 1, ww = w + kj - 1;
        if (hh < 0 || ww < 0) continue;
        float wk = wv[kk];
        v8s sv = *(const v8s*)(y3a + ((size_t)((n * 32 + hh) * 32 + ww)) * 128 + cg * 8);
#pragma unroll
        for (int e = 0; e < 8; ++e) acc[e] += wk * bf2f((u16)sv[e]);
    }
    v8u o;
#pragma unroll
    for (int e = 0; e < 8; ++e) o[e] = f2bf(acc[e]);
    *(v8u*)(out + (size_t)pix * 128 + cg * 8) = o;
}

// ---------------------------------------------------------------------------
extern "C" void kernel_launch(void* const* d_in, const int* in_sizes, int n_in,
                              void* d_out, int out_size, void* d_ws, size_t ws_size,
                              hipStream_t stream) {
    const float* x     = (const float*)d_in[0];
    const float* cv1_w = (const float*)d_in[1];
    const float* cv1_s = (const float*)d_in[2];
    const float* cv1_b = (const float*)d_in[3];
    const float* m1a_w = (const float*)d_in[4];
    const float* m1a_s = (const float*)d_in[5];
    const float* m1a_b = (const float*)d_in[6];
    const float* m1b_w = (const float*)d_in[7];
    const float* m1b_s = (const float*)d_in[8];
    const float* m1b_b = (const float*)d_in[9];
    const float* m2a_w = (const float*)d_in[10];
    const float* m2a_s = (const float*)d_in[11];
    const float* m2a_b = (const float*)d_in[12];
    const float* m2b_w = (const float*)d_in[13];
    const float* m2b_s = (const float*)d_in[14];
    const float* m2b_b = (const float*)d_in[15];
    const float* m3a_w = (const float*)d_in[16];
    const float* m3a_s = (const float*)d_in[17];
    const float* m3a_b = (const float*)d_in[18];
    const float* m3b_w = (const float*)d_in[19];
    const float* m3b_s = (const float*)d_in[20];
    const float* m3b_b = (const float*)d_in[21];
    const float* cvm2_w = (const float*)d_in[22];
    const float* cvm2_s = (const float*)d_in[23];
    const float* cvm2_b = (const float*)d_in[24];
    const float* cvm3_w = (const float*)d_in[25];
    const float* cvm3_s = (const float*)d_in[26];
    const float* cvm3_b = (const float*)d_in[27];
    // d_in[28..31]: u2_down_w/b, u2_enc_w/b — dead (k=1 softmax == 1)
    const float* u3_down_w = (const float*)d_in[32];
    const float* u3_down_b = (const float*)d_in[33];
    const float* u3_enc_w  = (const float*)d_in[34];
    const float* u3_enc_b  = (const float*)d_in[35];
    const float* cv2_w = (const float*)d_in[36];
    const float* cv2_s = (const float*)d_in[37];
    const float* cv2_b = (const float*)d_in[38];

    char* ws = (char*)d_ws;
    u16* A    = (u16*)(ws + 0);          // x_nhwc (67MB); later y2/y3
    u16* t    = (u16*)(ws + 67108864);   // 67MB
    u16* y1   = (u16*)(ws + 134217728);  // 33.5MB
    u16* bt   = (u16*)(ws + 167772160);  // 33.5MB bneck tmp
    u16* te   = (u16*)(ws + 201326592);  // 33.5MB y2b / y3b
    u16* y2a  = (u16*)(ws + 234881024);  // 8.4MB
    u16* y3a  = (u16*)(ws + 243269632);  // 2.1MB
    float* ktA = (float*)(ws + 245366784);  // 1MB fp32
    float* wts = (float*)(ws + 246415360);  // 2MB fp32
    u16* w3t  = (u16*)(ws + 248512512);  // 6 x 147456 bf16
    u16* wu2  = (u16*)(ws + 250281984);  // 65536 bf16
    u16* wu4  = (u16*)(ws + 250413056);  // 262144 bf16
    u16* wc1  = (u16*)(ws + 250937344);  // 65536 bf16
    u16* wc2  = (u16*)(ws + 251068416);  // 163840 bf16
    u16* y2 = A;
    u16* y3 = A + 16777216;

    dim3 B(256);
    // weight conversions / reshuffles
    wtrans3<<<576, B, 0, stream>>>(m1a_w, w3t + 0 * 147456);
    wtrans3<<<576, B, 0, stream>>>(m1b_w, w3t + 1 * 147456);
    wtrans3<<<576, B, 0, stream>>>(m2a_w, w3t + 2 * 147456);
    wtrans3<<<576, B, 0, stream>>>(m2b_w, w3t + 3 * 147456);
    wtrans3<<<576, B, 0, stream>>>(m3a_w, w3t + 4 * 147456);
    wtrans3<<<576, B, 0, stream>>>(m3b_w, w3t + 5 * 147456);
    wtrans_ps<<<256, B, 0, stream>>>(cvm2_w, wu2, 4);
    wtrans_ps<<<1024, B, 0, stream>>>(cvm3_w, wu4, 16);
    cvtw<<<256, B, 0, stream>>>(cv1_w, wc1, 65536);
    cvtw<<<640, B, 0, stream>>>(cv2_w, wc2, 163840);

    // x -> NHWC bf16
    nchw2nhwc<<<dim3(256, 4, 8), B, 0, stream>>>(x, A);

    // cv1 (1x1 256->256) -> t  (y = ch 0..127, y0 = ch 128..255)
    conv1_mfma<<<dim3(128, 2, 8), B, 0, stream>>>(A, 256, wc1, cv1_s, cv1_b, t, 256);

    // bneck1: y0 -> bt -> y1
    conv3_mfma<<<dim3(128, 8), B, 0, stream>>>(t, 128, 256, w3t + 0 * 147456, m1a_s, m1a_b, bt);
    conv3_mfma<<<dim3(128, 8), B, 0, stream>>>(bt, 0, 128, w3t + 1 * 147456, m1b_s, m1b_b, y1);

    // cvm2: pixel_unshuffle(y1,2) + 1x1 == 2x2/stride2 conv -> y2a (64x64)
    conv_mfma<2, 2, 2, 0, 128><<<dim3(64, 2, 8), B, 0, stream>>>(
        y1, 0, 128, wu2, cvm2_s, cvm2_b, y2a, 128, 128, 64, 128);

    // u2 carafe == nearest 2x upsample, + y1 -> te
    k_upadd<<<8192, B, 0, stream>>>(y2a, y1, te);

    // bneck2: te -> bt -> y2
    conv3_mfma<<<dim3(128, 8), B, 0, stream>>>(te, 0, 128, w3t + 2 * 147456, m2a_s, m2a_b, bt);
    conv3_mfma<<<dim3(128, 8), B, 0, stream>>>(bt, 0, 128, w3t + 3 * 147456, m2b_s, m2b_b, y2);

    // cvm3: pixel_unshuffle(y2,4) + 1x1 == 4x4/stride4 conv -> y3a (32x32)
    conv_mfma<4, 4, 4, 0, 128><<<dim3(16, 2, 8), B, 0, stream>>>(
        y2, 0, 128, wu4, cvm3_s, cvm3_b, y3a, 128, 128, 32, 128);

    // u3 carafe (k=2, up=4)
    k_u3down<<<1024, B, 0, stream>>>(y3a, u3_down_w, u3_down_b, ktA);
    k_u3enc<<<512, B, 0, stream>>>(ktA, u3_enc_w, u3_enc_b, wts);
    k_carafe<<<8192, B, 0, stream>>>(y3a, wts, y2, te);

    // bneck3: te -> bt -> y3
    conv3_mfma<<<dim3(128, 8), B, 0, stream>>>(te, 0, 128, w3t + 4 * 147456, m3a_s, m3a_b, bt);
    conv3_mfma<<<dim3(128, 8), B, 0, stream>>>(bt, 0, 128, w3t + 5 * 147456, m3b_s, m3b_b, y3);

    // cv2: 1x1 over concat [t, y1, y2, y3] -> d_out (NCHW fp32)
    cat_mfma<<<dim3(128, 2, 8), B, 0, stream>>>(t, y1, y2, y3, wc2, cv2_s, cv2_b, (float*)d_out);
}

// Round 5
// 1143.529 us; speedup vs baseline: 1.2136x; 1.0241x over previous
//
#include <hip/hip_runtime.h>

typedef unsigned short u16;
typedef short v8s __attribute__((ext_vector_type(8)));
typedef u16 v8u __attribute__((ext_vector_type(8)));
typedef float v4f __attribute__((ext_vector_type(4)));
typedef __bf16 v8bf __attribute__((ext_vector_type(8)));

__device__ __forceinline__ float bf2f(u16 u) {
    unsigned x = ((unsigned)u) << 16; float f; __builtin_memcpy(&f, &x, 4); return f;
}
__device__ __forceinline__ u16 f2bf(float f) {
    unsigned x; __builtin_memcpy(&x, &f, 4);
    x = x + 0x7FFFu + ((x >> 16) & 1u);
    return (u16)(x >> 16);
}
__device__ __forceinline__ float silu(float v) { return v / (1.f + __expf(-v)); }

// async global->LDS 16B per lane; l must be wave-uniform, data lands at l+lane*16
__device__ __forceinline__ void gld16(const void* g, void* l) {
    __builtin_amdgcn_global_load_lds(
        (const __attribute__((address_space(1))) unsigned int*)(uintptr_t)g,
        (__attribute__((address_space(3))) unsigned int*)(unsigned int)(uintptr_t)l,
        16, 0, 0);
}

// ---------------------------------------------------------------------------
// Weight conversion / reshuffle kernels (fp32 in -> bf16 out)
// ---------------------------------------------------------------------------
__global__ void cvtw(const float* __restrict__ in, u16* __restrict__ out, int n) {
    int i = blockIdx.x * 256 + threadIdx.x;
    if (i < n) out[i] = f2bf(in[i]);
}
// 3x3: in[co][ci][tap(9)] -> out[tap][co][ci]   (128x128x9)
__global__ void wtrans3(const float* __restrict__ in, u16* __restrict__ out) {
    int i = blockIdx.x * 256 + threadIdx.x;
    if (i >= 147456) return;
    int tap = i % 9; int rem = i / 9; int ci = rem & 127; int co = rem >> 7;
    out[((tap * 128 + co) << 7) + ci] = f2bf(in[i]);
}
// pixel-unshuffle 1x1: in[co][c*R2+tap] -> out[tap][co][c]  (co=128, c=128)
__global__ void wtrans_ps(const float* __restrict__ in, u16* __restrict__ out, int R2) {
    int i = blockIdx.x * 256 + threadIdx.x;
    int tap = i % R2; int rem = i / R2; int c = rem & 127; int co = rem >> 7;
    out[((tap * 128 + co) << 7) + c] = f2bf(in[i]);
}

// ---------------------------------------------------------------------------
// NCHW fp32 -> NHWC bf16 transpose for x (C=256, HW=16384)
// ---------------------------------------------------------------------------
__global__ __launch_bounds__(256) void nchw2nhwc(const float* __restrict__ in, u16* __restrict__ out) {
    __shared__ u16 tile[64][72];
    const int n = blockIdx.z, c0 = blockIdx.y * 64, p0 = blockIdx.x * 64;
#pragma unroll
    for (int rep = 0; rep < 16; ++rep) {
        int idx = rep * 256 + threadIdx.x;
        int c = idx >> 6, p = idx & 63;
        tile[c][p] = f2bf(in[((size_t)(n * 256 + c0 + c)) * 16384 + p0 + p]);
    }
    __syncthreads();
#pragma unroll
    for (int rep = 0; rep < 16; ++rep) {
        int idx = rep * 256 + threadIdx.x;
        int p = idx >> 6, c = idx & 63;
        out[((size_t)n * 16384 + p0 + p) * 256 + c0 + c] = tile[c][p];
    }
}

// ---------------------------------------------------------------------------
// conv3_mfma v5 (unchanged this round): 3x3 s1 p1, M=256 tile.
// ---------------------------------------------------------------------------
__global__ __launch_bounds__(256, 2) void conv3_mfma(
    const u16* __restrict__ src, int c0, int srcC,
    const u16* __restrict__ wt,  // [9][128][128]
    const float* __restrict__ scale, const float* __restrict__ bias,
    u16* __restrict__ out) {
    __shared__ __align__(16) char smem[65536];  // 2 x 32KB stage / 36KB epilogue
    const int bx = blockIdx.x, n = blockIdx.y;
    const int tile = ((bx & 7) << 3) | (bx >> 4);   // 0..63, 8 tiles per XCD
    const int co0 = ((bx >> 3) & 1) * 64;
    const int h0 = tile * 2;
    const int tid = threadIdx.x;
    const int lane = tid & 63, wv = tid >> 6;
    const int r = lane & 15, q = lane >> 4;
    const int wr = wv >> 1, wc = wv & 1;   // wr = output row, wc = co 32-half

    v4f acc[8][2];
#pragma unroll
    for (int a = 0; a < 8; ++a)
#pragma unroll
        for (int b = 0; b < 2; ++b) acc[a][b] = (v4f){0.f, 0.f, 0.f, 0.f};

    const size_t rowstride = (size_t)128 * srcC;  // u16 units
    const u16* nbase = src + (size_t)n * 128 * rowstride + c0;

    auto stage = [&](int buf, int k0) {
        const int hh = h0 - 1 + wv;              // wave-uniform
        char* base = smem + buf * 32768 + wv * 8192;
        if ((unsigned)hh < 128u) {
            const u16* g = nbase + (size_t)hh * rowstride + k0;
#pragma unroll
            for (int j = 0; j < 8; ++j) {
                int l = (j << 10) + lane * 16;   // linear byte off in 8KB row
                int sw = l ^ ((l >> 3) & 0x70);  // involution
                int px = sw >> 6, cb = sw & 63;
                gld16((const char*)(g + (size_t)px * srcC) + cb, base + (j << 10));
            }
        } else {
#pragma unroll
            for (int j = 0; j < 8; ++j)
                *(v8s*)(base + (j << 10) + lane * 16) = (v8s){0, 0, 0, 0, 0, 0, 0, 0};
        }
    };

    stage(0, 0);
    int buf = 0;
#pragma unroll
    for (int ch = 0; ch < 4; ++ch, buf ^= 1) {
        const int k0 = ch * 32;
        __syncthreads();  // drains vmcnt -> lds[buf] valid; buf^1 free to fill

        v8bf bfr[9][2];
#pragma unroll
        for (int tap = 0; tap < 9; ++tap)
#pragma unroll
            for (int nt = 0; nt < 2; ++nt)
                bfr[tap][nt] = __builtin_bit_cast(v8bf, *(const v8s*)(
                    wt + (size_t)((tap * 128 + co0 + wc * 32 + nt * 16 + r) << 7)
                       + k0 + q * 8));

        if (ch < 3) stage(buf ^ 1, k0 + 32);

        const char* abase = smem + buf * 32768;
#pragma unroll
        for (int tap = 0; tap < 9; ++tap) {
            const int kh = tap / 3, kw = tap % 3;
            const char* rbase = abase + ((wr + kh) << 13);  // input row wr+kh
#pragma unroll
            for (int mt = 0; mt < 8; ++mt) {
                int p = mt * 16 + r + kw - 1;        // px within the row
                bool vp = (unsigned)p < 128u;
                int pc = vp ? p : 0;
                int b = (pc << 6) + q * 16;
                b ^= (b >> 3) & 0x70;                // same involution
                v8s av = *(const v8s*)(rbase + b);
                if (!vp) av = (v8s){0, 0, 0, 0, 0, 0, 0, 0};
                v8bf af = __builtin_bit_cast(v8bf, av);
#pragma unroll
                for (int nt = 0; nt < 2; ++nt)
                    acc[mt][nt] = __builtin_amdgcn_mfma_f32_16x16x32_bf16(
                        af, bfr[tap][nt], acc[mt][nt], 0, 0, 0);
            }
        }
    }

    // epilogue: transpose through LDS ([256 px][72]), 16B coalesced stores
    __syncthreads();
    u16* ldsO = (u16*)smem;
#pragma unroll
    for (int nt = 0; nt < 2; ++nt) {
        int coL = wc * 32 + nt * 16 + r;
        int co = co0 + coL;
        float s = scale[co], bi = bias[co];
#pragma unroll
        for (int mt = 0; mt < 8; ++mt) {
#pragma unroll
            for (int i = 0; i < 4; ++i) {
                int p = wr * 128 + mt * 16 + q * 4 + i;
                ldsO[p * 72 + coL] = f2bf(silu(acc[mt][nt][i] * s + bi));
            }
        }
    }
    __syncthreads();
    const size_t obase = (size_t)n * 16384 + (size_t)h0 * 128;  // px index
#pragma unroll
    for (int rep = 0; rep < 8; ++rep) {
        int px = rep * 32 + (tid >> 3);     // 0..255 (2 rows contiguous NHWC)
        int c8 = (tid & 7) * 8;
        *(v8u*)(out + (obase + px) * 128 + co0 + c8) = *(const v8u*)&ldsO[px * 72 + c8];
    }
}

// ---------------------------------------------------------------------------
// conv1_mfma v4: 1x1 conv, K=srcC, output NHWC bf16.
// M=256 tile: block = 256px x 128co, 4 waves; wave = 128px x 64co,
// acc[8][4] = 128 VGPR. K-chunk 64: stage 256px x 64ci = 32KB, dbuf 64KB
// -> 2 blocks/CU. Compute/chunk/wave = 64 MFMA (2x v3) with half the
// barriers per output -> staging latency hidden (conv3-v5 recipe).
// B frags loaded after barrier BEFORE stage(next) (counted vmcnt).
// Epilogue: LDS transpose [256][136] (69.6KB) -> 16B coalesced stores.
// grid: (64, Cout/128, 8)
// ---------------------------------------------------------------------------
__global__ __launch_bounds__(256, 2) void conv1_mfma(
    const u16* __restrict__ src, int srcC,
    const u16* __restrict__ wt,  // [Cout][srcC]
    const float* __restrict__ scale, const float* __restrict__ bias,
    u16* __restrict__ out, int Cout) {
    __shared__ __align__(16) char smem[69632];  // 2x32KB stage / 69.6KB epilogue
    const int n = blockIdx.z, co0 = blockIdx.y * 128, px0 = blockIdx.x * 256;
    const int tid = threadIdx.x;
    const int lane = tid & 63, wv = tid >> 6;
    const int r = lane & 15, q = lane >> 4;
    const int wr = wv >> 1, wc = wv & 1;  // wr = px 128-half, wc = co 64-half

    v4f acc[8][4];
#pragma unroll
    for (int a = 0; a < 8; ++a)
#pragma unroll
        for (int b = 0; b < 4; ++b) acc[a][b] = (v4f){0.f, 0.f, 0.f, 0.f};

    const u16* abase = src + ((size_t)n * 16384 + px0) * srcC;

    // stage 256px x 64ci: linear o = j*4096 + tid*16, (px,cb) from swizzled o
    auto stage = [&](int buf, int k0) {
#pragma unroll
        for (int j = 0; j < 8; ++j) {
            int o = j * 4096 + tid * 16;
            int s2 = o ^ ((o >> 3) & 0x70);
            int px = s2 >> 7, cb = s2 & 127;
            gld16((const char*)(abase + (size_t)px * srcC + k0) + cb,
                  smem + buf * 32768 + j * 4096 + wv * 1024);
        }
    };

    stage(0, 0);
    int buf = 0;
    for (int k0 = 0; k0 < srcC; k0 += 64, buf ^= 1) {
        __syncthreads();  // lds[buf] valid; buf^1 free

        // B first (counted vmcnt), then stage(next): staging never drained
        v8bf bfr[2][4];
        const u16* wrow = wt + (size_t)(co0 + wc * 64 + r) * srcC + k0 + q * 8;
#pragma unroll
        for (int s = 0; s < 2; ++s)
#pragma unroll
            for (int nt = 0; nt < 4; ++nt)
                bfr[s][nt] = __builtin_bit_cast(v8bf,
                    *(const v8s*)(wrow + s * 32 + (size_t)nt * 16 * srcC));

        if (k0 + 64 < srcC) stage(buf ^ 1, k0 + 64);

#pragma unroll
        for (int s = 0; s < 2; ++s) {
#pragma unroll
            for (int mt = 0; mt < 8; ++mt) {
                int ba = buf * 32768 + (wr * 128 + mt * 16 + r) * 128 + s * 64 + q * 16;
                ba ^= (ba >> 3) & 0x70;
                v8bf af = __builtin_bit_cast(v8bf, *(const v8s*)(smem + ba));
#pragma unroll
                for (int nt = 0; nt < 4; ++nt)
                    acc[mt][nt] = __builtin_amdgcn_mfma_f32_16x16x32_bf16(
                        af, bfr[s][nt], acc[mt][nt], 0, 0, 0);
            }
        }
    }

    // epilogue: transpose through LDS [256][136], 16B coalesced stores
    __syncthreads();
    u16* ldsO = (u16*)smem;
#pragma unroll
    for (int nt = 0; nt < 4; ++nt) {
        int coL = wc * 64 + nt * 16 + r;
        int co = co0 + coL;
        float s = scale[co], bi = bias[co];
#pragma unroll
        for (int mt = 0; mt < 8; ++mt) {
#pragma unroll
            for (int i = 0; i < 4; ++i) {
                int p = wr * 128 + mt * 16 + q * 4 + i;
                ldsO[p * 136 + coL] = f2bf(silu(acc[mt][nt][i] * s + bi));
            }
        }
    }
    __syncthreads();
#pragma unroll
    for (int rep = 0; rep < 16; ++rep) {
        int px = rep * 16 + (tid >> 4);
        int c8 = (tid & 15) * 8;
        *(v8u*)(out + ((size_t)n * 16384 + px0 + px) * Cout + co0 + c8) =
            *(const v8u*)&ldsO[px * 136 + c8];
    }
}

// ---------------------------------------------------------------------------
// cat_mfma v4: cv2 = 1x1 over implicit concat [t(256), y1, y2, y3] -> 256.
// M=256 tile (conv3-v5 recipe): block = 256px x 128co, wave = 128px x 64co,
// acc[8][4]. 10 K-chunks of 64; stage 32KB dbuf 64KB -> 2 blocks/CU.
// 64 MFMA/wave/chunk (2x v3), half the barriers per output.
// Output NCHW fp32 (16B v4f stores, already coalesced-merged by L2).
// grid: (64, 2, 8)
// ---------------------------------------------------------------------------
__global__ __launch_bounds__(256, 2) void cat_mfma(
    const u16* __restrict__ s0, const u16* __restrict__ s1,
    const u16* __restrict__ s2, const u16* __restrict__ s3,
    const u16* __restrict__ wt,  // [256][640]
    const float* __restrict__ scale, const float* __restrict__ bias,
    float* __restrict__ out) {
    __shared__ __align__(16) char smem[65536];  // 2 x 32KB
    const int n = blockIdx.z, co0 = blockIdx.y * 128, px0 = blockIdx.x * 256;
    const int tid = threadIdx.x;
    const int lane = tid & 63, wv = tid >> 6;
    const int r = lane & 15, q = lane >> 4;
    const int wr = wv >> 1, wc = wv & 1;

    v4f acc[8][4];
#pragma unroll
    for (int a = 0; a < 8; ++a)
#pragma unroll
        for (int b = 0; b < 4; ++b) acc[a][b] = (v4f){0.f, 0.f, 0.f, 0.f};

    const u16* srcs[4] = {s0, s1, s2, s3};
    const int sCq[4] = {256, 128, 128, 128};
    const int kbq[4] = {0, 256, 384, 512};
    const int segs[10] = {0, 0, 0, 0, 1, 1, 2, 2, 3, 3};
    const int k0s[10] = {0, 64, 128, 192, 0, 64, 0, 64, 0, 64};

    auto stage = [&](int buf, int c) {
        int seg = segs[c]; int sc = sCq[seg]; int k0 = k0s[c];
        const u16* ab = srcs[seg] + ((size_t)n * 16384 + px0) * sc;
#pragma unroll
        for (int j = 0; j < 8; ++j) {
            int o = j * 4096 + tid * 16;
            int s2 = o ^ ((o >> 3) & 0x70);
            int px = s2 >> 7, cb = s2 & 127;
            gld16((const char*)(ab + (size_t)px * sc + k0) + cb,
                  smem + buf * 32768 + j * 4096 + wv * 1024);
        }
    };

    stage(0, 0);
    int buf = 0;
#pragma unroll
    for (int c = 0; c < 10; ++c, buf ^= 1) {
        __syncthreads();

        v8bf bfr[2][4];
        const u16* wrow = wt + (size_t)(co0 + wc * 64 + r) * 640 + kbq[segs[c]] + k0s[c] + q * 8;
#pragma unroll
        for (int s = 0; s < 2; ++s)
#pragma unroll
            for (int nt = 0; nt < 4; ++nt)
                bfr[s][nt] = __builtin_bit_cast(v8bf,
                    *(const v8s*)(wrow + s * 32 + (size_t)nt * 16 * 640));

        if (c < 9) stage(buf ^ 1, c + 1);

#pragma unroll
        for (int s = 0; s < 2; ++s) {
#pragma unroll
            for (int mt = 0; mt < 8; ++mt) {
                int ba = buf * 32768 + (wr * 128 + mt * 16 + r) * 128 + s * 64 + q * 16;
                ba ^= (ba >> 3) & 0x70;
                v8bf af = __builtin_bit_cast(v8bf, *(const v8s*)(smem + ba));
#pragma unroll
                for (int nt = 0; nt < 4; ++nt)
                    acc[mt][nt] = __builtin_amdgcn_mfma_f32_16x16x32_bf16(
                        af, bfr[s][nt], acc[mt][nt], 0, 0, 0);
            }
        }
    }

#pragma unroll
    for (int nt = 0; nt < 4; ++nt) {
        int co = co0 + wc * 64 + nt * 16 + r;
        float s = scale[co], bi = bias[co];
#pragma unroll
        for (int mt = 0; mt < 8; ++mt) {
            int p = px0 + wr * 128 + mt * 16 + q * 4;
            v4f o;
#pragma unroll
            for (int i = 0; i < 4; ++i) o[i] = silu(acc[mt][nt][i] * s + bi);
            *(v4f*)(out + (size_t)(n * 256 + co) * 16384 + p) = o;
        }
    }
}

// ---------------------------------------------------------------------------
// Generic MFMA conv (kept for cvm2/cvm3 strided taps; minor cost)
// ---------------------------------------------------------------------------
template <int KH, int KW, int S, int PAD, int CIN>
__global__ __launch_bounds__(256) void conv_mfma(
    const u16* __restrict__ src, int c0, int srcC,
    const u16* __restrict__ wt,
    const float* __restrict__ scale, const float* __restrict__ bias,
    u16* __restrict__ out, int Hin, int Win, int Wout, int Cout) {
    const int n = blockIdx.z;
    const int co0 = blockIdx.y * 64;
    const int hw0 = blockIdx.x * 64;
    const int tid = threadIdx.x;
    const int lane = tid & 63, wv = tid >> 6;
    const int r = lane & 15, q = lane >> 4;
    const int wr = wv >> 1, wc = wv & 1;

    const int m0 = hw0 + wr * 32 + r;
    const int m1 = m0 + 16;
    const int h0 = m0 / Wout, w0 = m0 - h0 * Wout;
    const int h1 = m1 / Wout, w1 = m1 - h1 * Wout;

    v4f acc00 = {0.f, 0.f, 0.f, 0.f}, acc01 = {0.f, 0.f, 0.f, 0.f};
    v4f acc10 = {0.f, 0.f, 0.f, 0.f}, acc11 = {0.f, 0.f, 0.f, 0.f};

    const u16* b0base = wt + (size_t)(co0 + wc * 32 + r) * CIN + q * 8;
    const size_t wtap = (size_t)Cout * CIN;

    int tap = 0;
#pragma unroll
    for (int kh = 0; kh < KH; ++kh)
#pragma unroll
        for (int kw = 0; kw < KW; ++kw, ++tap) {
            int ih0 = h0 * S + kh - PAD, iw0 = w0 * S + kw - PAD;
            int ih1 = h1 * S + kh - PAD, iw1 = w1 * S + kw - PAD;
            bool v0 = ((unsigned)ih0 < (unsigned)Hin) & ((unsigned)iw0 < (unsigned)Win);
            bool v1 = ((unsigned)ih1 < (unsigned)Hin) & ((unsigned)iw1 < (unsigned)Win);
            int p0i = v0 ? (n * Hin + ih0) * Win + iw0 : 0;
            int p1i = v1 ? (n * Hin + ih1) * Win + iw1 : 0;
            const u16* a0 = src + (size_t)p0i * srcC + c0 + q * 8;
            const u16* a1 = src + (size_t)p1i * srcC + c0 + q * 8;
            const u16* b0 = b0base + (size_t)tap * wtap;
            const u16* b1 = b0 + (size_t)16 * CIN;
#pragma unroll
            for (int k = 0; k < CIN; k += 32) {
                v8s za = {0, 0, 0, 0, 0, 0, 0, 0};
                v8s a0s = za, a1s = za;
                if (v0) a0s = *(const v8s*)(a0 + k);
                if (v1) a1s = *(const v8s*)(a1 + k);
                v8s b0s = *(const v8s*)(b0 + k);
                v8s b1s = *(const v8s*)(b1 + k);
                v8bf af0 = __builtin_bit_cast(v8bf, a0s);
                v8bf af1 = __builtin_bit_cast(v8bf, a1s);
                v8bf bw0 = __builtin_bit_cast(v8bf, b0s);
                v8bf bw1 = __builtin_bit_cast(v8bf, b1s);
                acc00 = __builtin_amdgcn_mfma_f32_16x16x32_bf16(af0, bw0, acc00, 0, 0, 0);
                acc01 = __builtin_amdgcn_mfma_f32_16x16x32_bf16(af0, bw1, acc01, 0, 0, 0);
                acc10 = __builtin_amdgcn_mfma_f32_16x16x32_bf16(af1, bw0, acc10, 0, 0, 0);
                acc11 = __builtin_amdgcn_mfma_f32_16x16x32_bf16(af1, bw1, acc11, 0, 0, 0);
            }
        }

    const int HWo = gridDim.x * 64;
#pragma unroll
    for (int ct = 0; ct < 2; ++ct) {
        v4f av0 = ct ? acc01 : acc00;
        v4f av1 = ct ? acc11 : acc10;
        int co = co0 + wc * 32 + ct * 16 + r;
        float s = scale[co], bb = bias[co];
        int mb = hw0 + wr * 32 + q * 4;
#pragma unroll
        for (int i = 0; i < 4; ++i) {
            float x0 = av0[i] * s + bb;
            float x1 = av1[i] * s + bb;
            out[((size_t)n * HWo + mb + i) * Cout + co] = f2bf(silu(x0));
            out[((size_t)n * HWo + mb + 16 + i) * Cout + co] = f2bf(silu(x1));
        }
    }
}

// ---------------------------------------------------------------------------
// u2 carafe == nearest 2x upsample (+ residual y1). NHWC bf16, C=128.
// ---------------------------------------------------------------------------
__global__ __launch_bounds__(256) void k_upadd(const u16* __restrict__ y2a,
                                               const u16* __restrict__ y1,
                                               u16* __restrict__ out) {
    int t = blockIdx.x * 256 + threadIdx.x;  // 2,097,152
    int cg = t & 15; int pix = t >> 4;
    int n = pix >> 14; int p = pix & 16383; int ho = p >> 7; int wo = p & 127;
    const u16* a = y2a + ((size_t)((n * 64 + (ho >> 1)) * 64 + (wo >> 1))) * 128 + cg * 8;
    const u16* b = y1 + (size_t)pix * 128 + cg * 8;
    v8s av = *(const v8s*)a;
    v8s bv = *(const v8s*)b;
    v8u o;
#pragma unroll
    for (int e = 0; e < 8; ++e) o[e] = f2bf(bf2f((u16)av[e]) + bf2f((u16)bv[e]));
    *(v8u*)(out + (size_t)pix * 128 + cg * 8) = o;
}

// ---------------------------------------------------------------------------
// u3 carafe pieces (small spatial, scalar fp32 math)
// ---------------------------------------------------------------------------
__global__ __launch_bounds__(256) void k_u3down(const u16* __restrict__ y3a,
                                                const float* __restrict__ w,
                                                const float* __restrict__ b,
                                                float* __restrict__ ktA) {
    int t = blockIdx.x * 256 + threadIdx.x;  // 262,144
    int co = t & 31; int pix = t >> 5;
    const u16* xr = y3a + (size_t)pix * 128;
    const float* wr = w + (size_t)co * 128;
    float acc = b[co];
#pragma unroll 16
    for (int k = 0; k < 128; ++k) acc += bf2f(xr[k]) * wr[k];
    ktA[t] = acc;
}

__global__ __launch_bounds__(256) void k_u3enc(const float* __restrict__ ktA,
                                               const float* __restrict__ ew,
                                               const float* __restrict__ eb,
                                               float* __restrict__ wtsm) {
    int t = blockIdx.x * 256 + threadIdx.x;  // 131,072
    int r = t & 15; int pix = t >> 4;
    int n = pix >> 10; int hw = pix & 1023; int h = hw >> 5; int w = hw & 31;
    float v[4];
#pragma unroll
    for (int kk = 0; kk < 4; ++kk) {
        int co = kk * 16 + r;
        float acc = eb[co];
#pragma unroll
        for (int dh = 0; dh < 2; ++dh)
#pragma unroll
            for (int dw = 0; dw < 2; ++dw) {
                int hh = h - 1 + dh, ww = w - 1 + dw;
                if (hh < 0 || ww < 0) continue;
                const float* kp = ktA + ((size_t)((n * 32 + hh) * 32 + ww)) * 32;
                const float* wp = ew + (size_t)co * 128 + dh * 2 + dw;
                for (int ci = 0; ci < 32; ++ci) acc += kp[ci] * wp[ci * 4];
            }
        v[kk] = acc;
    }
    float mx = fmaxf(fmaxf(v[0], v[1]), fmaxf(v[2], v[3]));
    float e0 = __expf(v[0] - mx), e1 = __expf(v[1] - mx), e2 = __expf(v[2] - mx), e3 = __expf(v[3] - mx);
    float inv = 1.f / (e0 + e1 + e2 + e3);
    float* o = wtsm + (size_t)t * 4;
    o[0] = e0 * inv; o[1] = e1 * inv; o[2] = e2 * inv; o[3] = e3 * inv;
}

__global__ __launch_bounds__(256) void k_carafe(const u16* __restrict__ y3a,
                                                const float* __restrict__ wtsm,
                                                const u16* __restrict__ y2,
                                                u16* __restrict__ out) {
    int t = blockIdx.x * 256 + threadIdx.x;  // 2,097,152
    int cg = t & 15; int pix = t >> 4;
    int n = pix >> 14; int p = pix & 16383; int ho = p >> 7; int wo = p & 127;
    int h = ho >> 2, i = ho & 3, w = wo >> 2, j = wo & 3, r = i * 4 + j;
    const float* wv = wtsm + ((size_t)((n * 1024 + h * 32 + w) * 16 + r)) * 4;
    v8s yv = *(const v8s*)(y2 + (size_t)pix * 128 + cg * 8);
    float acc[8];
#pragma unroll
    for (int e = 0; e < 8; ++e) acc[e] = bf2f((u16)yv[e]);
#pragma unroll
    for (int kk = 0; kk < 4; ++kk) {
        int ki = kk >> 1, kj = kk & 1;
        int hh = h + ki - 1, ww = w + kj - 1;
        if (hh < 0 || ww < 0) continue;
        float wk = wv[kk];
        v8s sv = *(const v8s*)(y3a + ((size_t)((n * 32 + hh) * 32 + ww)) * 128 + cg * 8);
#pragma unroll
        for (int e = 0; e < 8; ++e) acc[e] += wk * bf2f((u16)sv[e]);
    }
    v8u o;
#pragma unroll
    for (int e = 0; e < 8; ++e) o[e] = f2bf(acc[e]);
    *(v8u*)(out + (size_t)pix * 128 + cg * 8) = o;
}

// ---------------------------------------------------------------------------
extern "C" void kernel_launch(void* const* d_in, const int* in_sizes, int n_in,
                              void* d_out, int out_size, void* d_ws, size_t ws_size,
                              hipStream_t stream) {
    const float* x     = (const float*)d_in[0];
    const float* cv1_w = (const float*)d_in[1];
    const float* cv1_s = (const float*)d_in[2];
    const float* cv1_b = (const float*)d_in[3];
    const float* m1a_w = (const float*)d_in[4];
    const float* m1a_s = (const float*)d_in[5];
    const float* m1a_b = (const float*)d_in[6];
    const float* m1b_w = (const float*)d_in[7];
    const float* m1b_s = (const float*)d_in[8];
    const float* m1b_b = (const float*)d_in[9];
    const float* m2a_w = (const float*)d_in[10];
    const float* m2a_s = (const float*)d_in[11];
    const float* m2a_b = (const float*)d_in[12];
    const float* m2b_w = (const float*)d_in[13];
    const float* m2b_s = (const float*)d_in[14];
    const float* m2b_b = (const float*)d_in[15];
    const float* m3a_w = (const float*)d_in[16];
    const float* m3a_s = (const float*)d_in[17];
    const float* m3a_b = (const float*)d_in[18];
    const float* m3b_w = (const float*)d_in[19];
    const float* m3b_s = (const float*)d_in[20];
    const float* m3b_b = (const float*)d_in[21];
    const float* cvm2_w = (const float*)d_in[22];
    const float* cvm2_s = (const float*)d_in[23];
    const float* cvm2_b = (const float*)d_in[24];
    const float* cvm3_w = (const float*)d_in[25];
    const float* cvm3_s = (const float*)d_in[26];
    const float* cvm3_b = (const float*)d_in[27];
    // d_in[28..31]: u2_down_w/b, u2_enc_w/b — dead (k=1 softmax == 1)
    const float* u3_down_w = (const float*)d_in[32];
    const float* u3_down_b = (const float*)d_in[33];
    const float* u3_enc_w  = (const float*)d_in[34];
    const float* u3_enc_b  = (const float*)d_in[35];
    const float* cv2_w = (const float*)d_in[36];
    const float* cv2_s = (const float*)d_in[37];
    const float* cv2_b = (const float*)d_in[38];

    char* ws = (char*)d_ws;
    u16* A    = (u16*)(ws + 0);          // x_nhwc (67MB); later y2/y3
    u16* t    = (u16*)(ws + 67108864);   // 67MB
    u16* y1   = (u16*)(ws + 134217728);  // 33.5MB
    u16* bt   = (u16*)(ws + 167772160);  // 33.5MB bneck tmp
    u16* te   = (u16*)(ws + 201326592);  // 33.5MB y2b / y3b
    u16* y2a  = (u16*)(ws + 234881024);  // 8.4MB
    u16* y3a  = (u16*)(ws + 243269632);  // 2.1MB
    float* ktA = (float*)(ws + 245366784);  // 1MB fp32
    float* wts = (float*)(ws + 246415360);  // 2MB fp32
    u16* w3t  = (u16*)(ws + 248512512);  // 6 x 147456 bf16
    u16* wu2  = (u16*)(ws + 250281984);  // 65536 bf16
    u16* wu4  = (u16*)(ws + 250413056);  // 262144 bf16
    u16* wc1  = (u16*)(ws + 250937344);  // 65536 bf16
    u16* wc2  = (u16*)(ws + 251068416);  // 163840 bf16
    u16* y2 = A;
    u16* y3 = A + 16777216;

    dim3 B(256);
    // weight conversions / reshuffles
    wtrans3<<<576, B, 0, stream>>>(m1a_w, w3t + 0 * 147456);
    wtrans3<<<576, B, 0, stream>>>(m1b_w, w3t + 1 * 147456);
    wtrans3<<<576, B, 0, stream>>>(m2a_w, w3t + 2 * 147456);
    wtrans3<<<576, B, 0, stream>>>(m2b_w, w3t + 3 * 147456);
    wtrans3<<<576, B, 0, stream>>>(m3a_w, w3t + 4 * 147456);
    wtrans3<<<576, B, 0, stream>>>(m3b_w, w3t + 5 * 147456);
    wtrans_ps<<<256, B, 0, stream>>>(cvm2_w, wu2, 4);
    wtrans_ps<<<1024, B, 0, stream>>>(cvm3_w, wu4, 16);
    cvtw<<<256, B, 0, stream>>>(cv1_w, wc1, 65536);
    cvtw<<<640, B, 0, stream>>>(cv2_w, wc2, 163840);

    // x -> NHWC bf16
    nchw2nhwc<<<dim3(256, 4, 8), B, 0, stream>>>(x, A);

    // cv1 (1x1 256->256) -> t  (y = ch 0..127, y0 = ch 128..255)
    conv1_mfma<<<dim3(64, 2, 8), B, 0, stream>>>(A, 256, wc1, cv1_s, cv1_b, t, 256);

    // bneck1: y0 -> bt -> y1
    conv3_mfma<<<dim3(128, 8), B, 0, stream>>>(t, 128, 256, w3t + 0 * 147456, m1a_s, m1a_b, bt);
    conv3_mfma<<<dim3(128, 8), B, 0, stream>>>(bt, 0, 128, w3t + 1 * 147456, m1b_s, m1b_b, y1);

    // cvm2: pixel_unshuffle(y1,2) + 1x1 == 2x2/stride2 conv -> y2a (64x64)
    conv_mfma<2, 2, 2, 0, 128><<<dim3(64, 2, 8), B, 0, stream>>>(
        y1, 0, 128, wu2, cvm2_s, cvm2_b, y2a, 128, 128, 64, 128);

    // u2 carafe == nearest 2x upsample, + y1 -> te
    k_upadd<<<8192, B, 0, stream>>>(y2a, y1, te);

    // bneck2: te -> bt -> y2
    conv3_mfma<<<dim3(128, 8), B, 0, stream>>>(te, 0, 128, w3t + 2 * 147456, m2a_s, m2a_b, bt);
    conv3_mfma<<<dim3(128, 8), B, 0, stream>>>(bt, 0, 128, w3t + 3 * 147456, m2b_s, m2b_b, y2);

    // cvm3: pixel_unshuffle(y2,4) + 1x1 == 4x4/stride4 conv -> y3a (32x32)
    conv_mfma<4, 4, 4, 0, 128><<<dim3(16, 2, 8), B, 0, stream>>>(
        y2, 0, 128, wu4, cvm3_s, cvm3_b, y3a, 128, 128, 32, 128);

    // u3 carafe (k=2, up=4)
    k_u3down<<<1024, B, 0, stream>>>(y3a, u3_down_w, u3_down_b, ktA);
    k_u3enc<<<512, B, 0, stream>>>(ktA, u3_enc_w, u3_enc_b, wts);
    k_carafe<<<8192, B, 0, stream>>>(y3a, wts, y2, te);

    // bneck3: te -> bt -> y3
    conv3_mfma<<<dim3(128, 8), B, 0, stream>>>(te, 0, 128, w3t + 4 * 147456, m3a_s, m3a_b, bt);
    conv3_mfma<<<dim3(128, 8), B, 0, stream>>>(bt, 0, 128, w3t + 5 * 147456, m3b_s, m3b_b, y3);

    // cv2: 1x1 over concat [t, y1, y2, y3] -> d_out (NCHW fp32)
    cat_mfma<<<dim3(64, 2, 8), B, 0, stream>>>(t, y1, y2, y3, wc2, cv2_s, cv2_b, (float*)d_out);
}